// Round 11
// baseline (297.895 us; speedup 1.0000x reference)
//
#include <hip/hip_runtime.h>
#include <hip/hip_fp16.h>
#include <math.h>

#define NH 8
#define DH 80
#define NTOK 2048
#define QD 640
#define SCALE_F 0.11180339887498949f
#define TSCALE_F (1.2f * SCALE_F)
#define GAMMA_F 0.3f
#define LMAX_F 2.5f
#define TOPKN 128
#define NZ 8

typedef __attribute__((ext_vector_type(8))) short bf16x8;
typedef __attribute__((ext_vector_type(4))) float f32x4;
typedef __attribute__((ext_vector_type(4))) unsigned short u16x4;

// ---- ws float offsets ----
#define OFF_QB   0u            // f32 [8][2048][80]
#define OFF_OB   1310720u      // f32 [2048][640]
#define OFF_QH   2621440u      // bf16 [8][2048][96]
#define OFF_QL   3407872u
#define OFF_KCH  4194304u
#define OFF_KSH  4980736u
#define OFF_KSL  5767168u
#define OFF_VCT  6553600u      // bf16 VT_c  [8][80][2048]
#define OFF_VCQT 7208960u
#define OFF_VST  7864320u
#define OFF_VSQT 8519680u
#define OFF_OP   9175040u      // fp16 [8][8][2048][80] (5242880 floats)
#define OFF_SP   14417920u     // fp16 [8][8][2048][80]
#define OFF_DEN  19660800u     // f32 [8][8][2048] = 131072
#define OFF_MSZ  19791872u
#define OFF_LSZ  19922944u
#define OFF_MCZ  20054016u
#define OFF_LCZ  20185088u
#define OFF_M    20316160u     // f32 [8][2048]
#define OFF_LAM  20332544u
#define OFF_THR  20334592u
#define OFF_MU   20350976u
#define OFF_RSTD 20351616u
#define OFF_S16  20352256u     // fp16 style   S [8][2048][2048]
#define OFF_SC16 37129472u     // fp16 content S [8][2048][2048]

static __device__ __forceinline__ unsigned short f2bf(float f) {
  unsigned u = __float_as_uint(f);
  return (unsigned short)((u + 0x7FFFu + ((u >> 16) & 1u)) >> 16);
}
static __device__ __forceinline__ float bf2f(unsigned short s) {
  return __uint_as_float(((unsigned)s) << 16);
}
static __device__ __forceinline__ unsigned sk16(unsigned u) {
  return (u & 0x8000u) ? (~u & 0xFFFFu) : (u | 0x8000u);
}

// ---------------- split-bf16 MFMA projection GEMM ---------------------------
__global__ __launch_bounds__(256) void k_projmm(
    const float* __restrict__ x, const float* __restrict__ Wq,
    const float* __restrict__ Wk, const float* __restrict__ Wv,
    const float* __restrict__ Qc, float* __restrict__ qb,
    unsigned short* __restrict__ qh_, unsigned short* __restrict__ ql_,
    unsigned short* __restrict__ kch_,
    unsigned short* __restrict__ vct_, unsigned short* __restrict__ vcqt_)
{
  const float* W = (blockIdx.z == 0) ? Wq : ((blockIdx.z == 1) ? Wk : Wv);
  const int n0 = blockIdx.y * 64, c0 = blockIdx.x * 64;
  const int tid = threadIdx.x;
  const int w = tid >> 6, l = tid & 63;
  const int cc = l & 15, g = l >> 4;
  const bool full3 = (blockIdx.z == 0);

  __shared__ unsigned short sXh[64 * 72];
  __shared__ unsigned short sXl[64 * 72];
  __shared__ unsigned short sWh[64 * 72];
  __shared__ unsigned short sWl[64 * 72];

  f32x4 D[4];
#pragma unroll
  for (int ct = 0; ct < 4; ++ct) D[ct] = (f32x4){0.f, 0.f, 0.f, 0.f};

  for (int k0 = 0; k0 < QD; k0 += 64) {
    __syncthreads();
#pragma unroll
    for (int it = 0; it < 4; ++it) {
      int f = tid + it * 256;
      int row = f >> 4, col4 = f & 15;
      float4 xa = *(const float4*)(x + (size_t)(n0 + row) * QD + k0 + col4 * 4);
      float4 wa = *(const float4*)(W + (size_t)(c0 + row) * QD + k0 + col4 * 4);
      u16x4 xh, xl, wh, wl;
      float xv[4] = {xa.x, xa.y, xa.z, xa.w};
      float wv[4] = {wa.x, wa.y, wa.z, wa.w};
#pragma unroll
      for (int j = 0; j < 4; ++j) {
        unsigned short h1 = f2bf(xv[j]);
        xh[j] = h1; xl[j] = f2bf(xv[j] - bf2f(h1));
        unsigned short h2 = f2bf(wv[j]);
        wh[j] = h2; wl[j] = f2bf(wv[j] - bf2f(h2));
      }
      *(u16x4*)&sXh[row * 72 + col4 * 4] = xh;
      *(u16x4*)&sXl[row * 72 + col4 * 4] = xl;
      *(u16x4*)&sWh[row * 72 + col4 * 4] = wh;
      *(u16x4*)&sWl[row * 72 + col4 * 4] = wl;
    }
    __syncthreads();
    bf16x8 ah[2], al[2];
#pragma unroll
    for (int kc = 0; kc < 2; ++kc) {
      ah[kc] = *(const bf16x8*)&sXh[(w * 16 + cc) * 72 + kc * 32 + g * 8];
      al[kc] = *(const bf16x8*)&sXl[(w * 16 + cc) * 72 + kc * 32 + g * 8];
    }
#pragma unroll
    for (int ct = 0; ct < 4; ++ct) {
#pragma unroll
      for (int kc = 0; kc < 2; ++kc) {
        bf16x8 bh = *(const bf16x8*)&sWh[(ct * 16 + cc) * 72 + kc * 32 + g * 8];
        bf16x8 bl = *(const bf16x8*)&sWl[(ct * 16 + cc) * 72 + kc * 32 + g * 8];
        D[ct] = __builtin_amdgcn_mfma_f32_16x16x32_bf16(ah[kc], bh, D[ct], 0, 0, 0);
        D[ct] = __builtin_amdgcn_mfma_f32_16x16x32_bf16(ah[kc], bl, D[ct], 0, 0, 0);
        if (full3)
          D[ct] = __builtin_amdgcn_mfma_f32_16x16x32_bf16(al[kc], bh, D[ct], 0, 0, 0);
      }
    }
  }
#pragma unroll
  for (int ct = 0; ct < 4; ++ct) {
#pragma unroll
    for (int r = 0; r < 4; ++r) {
      int n = n0 + w * 16 + g * 4 + r;
      int ccol = c0 + ct * 16 + cc;
      int h = ccol / DH, d = ccol - h * DH;
      size_t i80 = ((size_t)h * NTOK + n) * 80 + d;
      size_t i96 = ((size_t)h * NTOK + n) * 96 + d;
      float val = D[ct][r];
      if (blockIdx.z == 0) {
        val = GAMMA_F * Qc[i80] + (1.f - GAMMA_F) * val;
        qb[i80] = val;
        unsigned short hs = f2bf(val);
        qh_[i96] = hs;
        ql_[i96] = f2bf(val - bf2f(hs));
      } else if (blockIdx.z == 1) {
        kch_[i96] = f2bf(val);
      } else {
        size_t iT = (((size_t)h * 80 + d) << 11) + n;
        vct_[iT]  = f2bf(val);
        vcqt_[iT] = f2bf(val * val);
      }
    }
  }
}

// ---------------- style inputs: K split + pads; V transposed to VT ----------
__global__ __launch_bounds__(256) void k_cvt(
    const float* __restrict__ Ks, const float* __restrict__ Vs,
    unsigned short* __restrict__ Ksh, unsigned short* __restrict__ Ksl,
    unsigned short* __restrict__ VTs, unsigned short* __restrict__ VTqs,
    unsigned short* __restrict__ qh_, unsigned short* __restrict__ ql_,
    unsigned short* __restrict__ kch_)
{
  const int h = blockIdx.y;
  const int n0 = blockIdx.x * 64;
  const int tid = threadIdx.x;
  __shared__ unsigned short sVT[80 * 68];
  __shared__ unsigned short sVQ[80 * 68];

  for (int f = tid; f < 1280; f += 256) {
    int rr = f / 20, dc = f % 20;
    size_t i80 = ((size_t)h * NTOK + n0 + rr) * 80 + dc * 4;
    size_t i96 = ((size_t)h * NTOK + n0 + rr) * 96 + dc * 4;
    float4 kv = *(const float4*)(Ks + i80);
    float kvv[4] = {kv.x, kv.y, kv.z, kv.w};
    u16x4 kh, kl;
#pragma unroll
    for (int j = 0; j < 4; ++j) {
      unsigned short hs = f2bf(kvv[j]);
      kh[j] = hs; kl[j] = f2bf(kvv[j] - bf2f(hs));
    }
    *(u16x4*)(Ksh + i96) = kh;
    *(u16x4*)(Ksl + i96) = kl;
    float4 vv = *(const float4*)(Vs + i80);
    float vvv[4] = {vv.x, vv.y, vv.z, vv.w};
#pragma unroll
    for (int j = 0; j < 4; ++j) {
      int d = dc * 4 + j;
      sVT[d * 68 + rr] = f2bf(vvv[j]);
      sVQ[d * 68 + rr] = f2bf(vvv[j] * vvv[j]);
    }
  }
  for (int f = tid; f < 1024; f += 256) {
    int rr = f >> 4, dcol = 80 + (f & 15);
    size_t i96 = ((size_t)h * NTOK + n0 + rr) * 96 + dcol;
    Ksh[i96] = 0; Ksl[i96] = 0; qh_[i96] = 0; ql_[i96] = 0; kch_[i96] = 0;
  }
  __syncthreads();
  for (int f = tid; f < 640; f += 256) {
    int d = f >> 3, kp8 = f & 7;
    size_t iT = (((size_t)h * 80 + d) << 11) + n0 + kp8 * 8;
    *(bf16x8*)(VTs + iT)  = *(const bf16x8*)&sVT[d * 68 + kp8 * 8];
    *(bf16x8*)(VTqs + iT) = *(const bf16x8*)&sVQ[d * 68 + kp8 * 8];
  }
}

// ---------------- per-(h,d) mean / rstd of q over tokens --------------------
__global__ __launch_bounds__(128) void k_qstats(
    const float* __restrict__ qb, float* __restrict__ mu, float* __restrict__ rstd)
{
  const int h = blockIdx.x / DH, d = blockIdx.x % DH;
  const int tid = threadIdx.x;
  float s = 0.f, s2 = 0.f;
  for (int n = tid; n < NTOK; n += 128) {
    float v = qb[((size_t)h * NTOK + n) * 80 + d];
    s += v; s2 = fmaf(v, v, s2);
  }
#pragma unroll
  for (int off = 32; off; off >>= 1) { s += __shfl_xor(s, off, 64); s2 += __shfl_xor(s2, off, 64); }
  __shared__ float sh[4];
  if ((tid & 63) == 0) { sh[(tid >> 6) * 2] = s; sh[(tid >> 6) * 2 + 1] = s2; }
  __syncthreads();
  if (tid == 0) {
    float S = sh[0] + sh[2], S2 = sh[1] + sh[3];
    float mval = S * (1.f / NTOK);
    float var = S2 * (1.f / NTOK) - mval * mval;
    mu[h * DH + d] = mval;
    rstd[h * DH + d] = rsqrtf(var + 1e-5f);
  }
}

// ---------------- pass A (z=8, XCD-swizzled): logits -> fp16 S/Sc; LSE ------
// Fixed-base LSE; direct scalar global S stores (measured best in R9).
__global__ __launch_bounds__(256) void k_passA(
    const unsigned short* __restrict__ qh_, const unsigned short* __restrict__ ql_,
    const unsigned short* __restrict__ Ksh, const unsigned short* __restrict__ Ksl,
    const unsigned short* __restrict__ kch_,
    unsigned short* __restrict__ S16, unsigned short* __restrict__ Sc16,
    float* __restrict__ mSz, float* __restrict__ lSz,
    float* __restrict__ mCz, float* __restrict__ lCz)
{
  const int bid = blockIdx.x;
  const int swz = (bid & 7) * 256 + (bid >> 3);   // 2048 % 8 == 0: bijective
  const int q0 = (swz & 31) * 64;
  const int h  = (swz >> 5) & 7;
  const int z  = swz >> 8;                        // 0..7
  const int tid = threadIdx.x;
  const int w = tid >> 6, l = tid & 63;
  const int c = l & 15, g = l >> 4;

  __shared__ unsigned short sKh[64 * 104];
  __shared__ unsigned short sKl[64 * 104];

  bf16x8 qhf[3], qlf[3];
  {
    const size_t qrow = ((size_t)h * NTOK + q0 + w * 16 + c) * 96;
#pragma unroll
    for (int kc = 0; kc < 3; ++kc) {
      qhf[kc] = *(const bf16x8*)(qh_ + qrow + kc * 32 + g * 8);
      qlf[kc] = *(const bf16x8*)(ql_ + qrow + kc * 32 + g * 8);
    }
  }
  float m[4], lse[4], mc[4], lc[4];
#pragma unroll
  for (int r = 0; r < 4; ++r) { m[r] = -INFINITY; lse[r] = 0.f; mc[r] = -INFINITY; lc[r] = 0.f; }

  // ---- style: 4 key tiles of 64 ----
  for (int t = 0; t < 4; ++t) {
    const size_t kbase = ((size_t)h * NTOK + z * 256 + t * 64) * 96;
    __syncthreads();
    for (int f = tid; f < 768; f += 256) {
      int row = f / 12, ch = f % 12;
      *(bf16x8*)(sKh + row * 104 + ch * 8) = *(const bf16x8*)(Ksh + kbase + row * 96 + ch * 8);
      *(bf16x8*)(sKl + row * 104 + ch * 8) = *(const bf16x8*)(Ksl + kbase + row * 96 + ch * 8);
    }
    __syncthreads();
#pragma unroll
    for (int ct = 0; ct < 4; ++ct) {
      f32x4 D = {0.f, 0.f, 0.f, 0.f};
      const int krow = (ct * 16 + c) * 104 + g * 8;
#pragma unroll
      for (int kc = 0; kc < 3; ++kc) {
        bf16x8 bh = *(const bf16x8*)(sKh + krow + kc * 32);
        D = __builtin_amdgcn_mfma_f32_16x16x32_bf16(qhf[kc], bh, D, 0, 0, 0);
      }
#pragma unroll
      for (int kc = 0; kc < 3; ++kc) {
        bf16x8 bl = *(const bf16x8*)(sKl + krow + kc * 32);
        D = __builtin_amdgcn_mfma_f32_16x16x32_bf16(qhf[kc], bl, D, 0, 0, 0);
      }
#pragma unroll
      for (int kc = 0; kc < 3; ++kc) {
        bf16x8 bh = *(const bf16x8*)(sKh + krow + kc * 32);
        D = __builtin_amdgcn_mfma_f32_16x16x32_bf16(qlf[kc], bh, D, 0, 0, 0);
      }
#pragma unroll
      for (int r = 0; r < 4; ++r) {
        float s = D[r] * TSCALE_F;
        S16[((size_t)h * NTOK + q0 + w * 16 + g * 4 + r) * 2048 + z * 256 + t * 64 + ct * 16 + c] =
            __half_as_ushort(__float2half(s));
        lse[r] += __expf(s);
        m[r] = fmaxf(m[r], s);
      }
    }
  }
  // ---- content: 4 key tiles ----
  for (int t = 0; t < 4; ++t) {
    const size_t kbase = ((size_t)h * NTOK + z * 256 + t * 64) * 96;
    __syncthreads();
    for (int f = tid; f < 768; f += 256) {
      int row = f / 12, ch = f % 12;
      *(bf16x8*)(sKh + row * 104 + ch * 8) = *(const bf16x8*)(kch_ + kbase + row * 96 + ch * 8);
    }
    __syncthreads();
#pragma unroll
    for (int ct = 0; ct < 4; ++ct) {
      f32x4 D = {0.f, 0.f, 0.f, 0.f};
      const int krow = (ct * 16 + c) * 104 + g * 8;
#pragma unroll
      for (int kc = 0; kc < 3; ++kc) {
        bf16x8 bh = *(const bf16x8*)(sKh + krow + kc * 32);
        D = __builtin_amdgcn_mfma_f32_16x16x32_bf16(qhf[kc], bh, D, 0, 0, 0);
      }
#pragma unroll
      for (int r = 0; r < 4; ++r) {
        float s = D[r] * SCALE_F;
        Sc16[((size_t)h * NTOK + q0 + w * 16 + g * 4 + r) * 2048 + z * 256 + t * 64 + ct * 16 + c] =
            __half_as_ushort(__float2half(s));
        lc[r] += __expf(s);
        mc[r] = fmaxf(mc[r], s);
      }
    }
  }
  // merge across the 16 col-lanes
#pragma unroll
  for (int off = 1; off < 16; off <<= 1) {
#pragma unroll
    for (int r = 0; r < 4; ++r) {
      lse[r] += __shfl_xor(lse[r], off, 64);
      m[r] = fmaxf(m[r], __shfl_xor(m[r], off, 64));
      lc[r] += __shfl_xor(lc[r], off, 64);
      mc[r] = fmaxf(mc[r], __shfl_xor(mc[r], off, 64));
    }
  }
  if (c == 0) {
    size_t base = (size_t)(z * 8 + h) * NTOK + q0 + w * 16 + g * 4;
#pragma unroll
    for (int r = 0; r < 4; ++r) {
      mSz[base + r] = m[r]; lSz[base + r] = lse[r];
      mCz[base + r] = mc[r]; lCz[base + r] = lc[r];
    }
  }
}

// ---------------- gate: combine 8 z-slices (fixed-base sums), lambda, M -----
__global__ __launch_bounds__(256) void k_gate(
    const float* __restrict__ mSz, const float* __restrict__ lSz,
    const float* __restrict__ mCz, const float* __restrict__ lCz,
    float* __restrict__ M_, float* __restrict__ lam_)
{
  int n = blockIdx.x * 256 + threadIdx.x;
  if (n >= NTOK) return;
  float msf[NH], mcf[NH], sum = 0.f;
#pragma unroll
  for (int h = 0; h < NH; ++h) {
    float mm = -INFINITY, cm = -INFINITY, ls = 0.f, lcs = 0.f;
#pragma unroll
    for (int zz = 0; zz < NZ; ++zz) {
      mm = fmaxf(mm, mSz[(size_t)(zz * 8 + h) * NTOK + n]);
      cm = fmaxf(cm, mCz[(size_t)(zz * 8 + h) * NTOK + n]);
      ls  += lSz[(size_t)(zz * 8 + h) * NTOK + n];
      lcs += lCz[(size_t)(zz * 8 + h) * NTOK + n];
    }
    float lse_s = __logf(ls);
    float lse_c = __logf(lcs);
    msf[h] = mm; mcf[h] = cm;
    sum += fminf(fmaxf(lse_s - lse_c, -20.f), 20.f);
  }
  float lam = 1.f + (LMAX_F - 1.f) * (1.f / (1.f + __expf(-sum * (1.f / NH))));
  lam_[n] = lam;
#pragma unroll
  for (int h = 0; h < NH; ++h)
    M_[h * NTOK + n] = fmaxf(lam * msf[h], mcf[h]);
}

// ---------------- top-k threshold: 16-bit ballot bisection on fp16 S --------
__global__ __launch_bounds__(512) void k_topk(const unsigned short* __restrict__ S16,
                                              unsigned* __restrict__ thr_)
{
  const int h = blockIdx.y;
  const int n = blockIdx.x * 8 + (threadIdx.x >> 6);
  const int l = threadIdx.x & 63;
  const unsigned short* Srow = S16 + ((size_t)h * NTOK + n) * 2048;
  unsigned kv[32];
#pragma unroll
  for (int t = 0; t < 4; ++t) {
    uint4 v = ((const uint4*)Srow)[t * 64 + l];
    unsigned dw[4] = {v.x, v.y, v.z, v.w};
#pragma unroll
    for (int i = 0; i < 8; ++i) {
      unsigned u = (dw[i >> 1] >> ((i & 1) * 16)) & 0xFFFFu;
      kv[t * 8 + i] = sk16(u);
    }
  }
  unsigned klo = 0u, khi = 65536u;
  for (int it = 0; it < 16; ++it) {
    unsigned mid = (klo + khi) >> 1;
    int cnt = 0;
#pragma unroll
    for (int t = 0; t < 32; ++t)
      cnt += __popcll(__ballot(kv[t] >= mid));
    if (cnt == TOPKN) { klo = mid; break; }
    if (cnt > TOPKN) klo = mid; else khi = mid;
    if (khi - klo <= 1u) break;
  }
  if (l == 0) thr_[h * NTOK + n] = klo;
}

// ---------------- pass B (z=8): pure PV, fp16 partial outputs ---------------
__global__ __launch_bounds__(256) void k_passB(
    const unsigned short* __restrict__ VTs, const unsigned short* __restrict__ VTqs,
    const unsigned short* __restrict__ VTc, const unsigned short* __restrict__ VTqc,
    const unsigned short* __restrict__ S16, const unsigned short* __restrict__ Sc16,
    const float* __restrict__ M_, const float* __restrict__ lam_,
    const unsigned* __restrict__ thr_,
    unsigned short* __restrict__ oP, unsigned short* __restrict__ sP,
    float* __restrict__ denP)
{
  const int bid = blockIdx.x;
  const int swz = (bid & 7) * 256 + (bid >> 3);
  const int q0 = (swz & 31) * 64;
  const int h  = (swz >> 5) & 7;
  const int z  = swz >> 8;
  const int tid = threadIdx.x;
  const int w = tid >> 6, l = tid & 63;
  const int c = l & 15, g = l >> 4;

  __shared__ unsigned short vT[80 * 72];
  __shared__ unsigned short vqT[80 * 72];

  const int myrow = w * 16 + c;
  const float myM = M_[h * NTOK + q0 + myrow];
  const float myLam = lam_[q0 + myrow];
  const unsigned myThr = thr_[h * NTOK + q0 + myrow];

  const size_t srow = ((size_t)h * NTOK + q0 + myrow) * 2048 + g * 8;
  const int d0 = tid >> 3, kp8 = tid & 7;
  const size_t vr0 = (((size_t)h * 80 + d0) << 11) + kp8 * 8;
  const size_t vr1 = (((size_t)h * 80 + d0 + 32) << 11) + kp8 * 8;
  const size_t vr2 = (((size_t)h * 80 + d0 + 64) << 11) + kp8 * 8;
  const bool third = (tid < 128);

  f32x4 oacc[5], sacc[5];
#pragma unroll
  for (int dt = 0; dt < 5; ++dt) { oacc[dt] = (f32x4){0.f,0.f,0.f,0.f}; sacc[dt] = (f32x4){0.f,0.f,0.f,0.f}; }
  float den = 0.f;

  for (int t = 0; t < 8; ++t) {
    const bool style = (t < 4);
    const int k0 = z * 256 + (t & 3) * 64;
    const unsigned short* Sp = style ? S16 : Sc16;
    const unsigned short* Vp = style ? VTs : VTc;
    const unsigned short* Vq = style ? VTqs : VTqc;
    uint4 s0 = *(const uint4*)(Sp + srow + k0);
    uint4 s1 = *(const uint4*)(Sp + srow + k0 + 32);
    bf16x8 v0 = *(const bf16x8*)(Vp + vr0 + k0);
    bf16x8 v1 = *(const bf16x8*)(Vp + vr1 + k0);
    bf16x8 u0 = *(const bf16x8*)(Vq + vr0 + k0);
    bf16x8 u1 = *(const bf16x8*)(Vq + vr1 + k0);
    bf16x8 v2, u2;
    if (third) {
      v2 = *(const bf16x8*)(Vp + vr2 + k0);
      u2 = *(const bf16x8*)(Vq + vr2 + k0);
    }
    __syncthreads();
    *(bf16x8*)&vT[d0 * 72 + kp8 * 8] = v0;
    *(bf16x8*)&vqT[d0 * 72 + kp8 * 8] = u0;
    *(bf16x8*)&vT[(d0 + 32) * 72 + kp8 * 8] = v1;
    *(bf16x8*)&vqT[(d0 + 32) * 72 + kp8 * 8] = u1;
    if (third) {
      *(bf16x8*)&vT[(d0 + 64) * 72 + kp8 * 8] = v2;
      *(bf16x8*)&vqT[(d0 + 64) * 72 + kp8 * 8] = u2;
    }
    __syncthreads();
    bf16x8 pa0, pa1;
    {
      unsigned dw0[4] = {s0.x, s0.y, s0.z, s0.w};
      unsigned dw1[4] = {s1.x, s1.y, s1.z, s1.w};
#pragma unroll
      for (int i = 0; i < 8; ++i) {
        unsigned ua = (dw0[i >> 1] >> ((i & 1) * 16)) & 0xFFFFu;
        float sa = __half2float(__ushort_as_half((unsigned short)ua));
        float wa = style ? ((sk16(ua) >= myThr) ? __expf(myLam * sa - myM) : 0.f)
                         : __expf(sa - myM);
        den += wa;
        pa0[i] = (short)f2bf(wa);
        unsigned ub = (dw1[i >> 1] >> ((i & 1) * 16)) & 0xFFFFu;
        float sb = __half2float(__ushort_as_half((unsigned short)ub));
        float wb = style ? ((sk16(ub) >= myThr) ? __expf(myLam * sb - myM) : 0.f)
                         : __expf(sb - myM);
        den += wb;
        pa1[i] = (short)f2bf(wb);
      }
    }
#pragma unroll
    for (int dt = 0; dt < 5; ++dt) {
      bf16x8 bv0  = *(const bf16x8*)&vT[(dt * 16 + c) * 72 + g * 8];
      bf16x8 bvq0 = *(const bf16x8*)&vqT[(dt * 16 + c) * 72 + g * 8];
      bf16x8 bv1  = *(const bf16x8*)&vT[(dt * 16 + c) * 72 + 32 + g * 8];
      bf16x8 bvq1 = *(const bf16x8*)&vqT[(dt * 16 + c) * 72 + 32 + g * 8];
      oacc[dt] = __builtin_amdgcn_mfma_f32_16x16x32_bf16(pa0, bv0, oacc[dt], 0, 0, 0);
      sacc[dt] = __builtin_amdgcn_mfma_f32_16x16x32_bf16(pa0, bvq0, sacc[dt], 0, 0, 0);
      oacc[dt] = __builtin_amdgcn_mfma_f32_16x16x32_bf16(pa1, bv1, oacc[dt], 0, 0, 0);
      sacc[dt] = __builtin_amdgcn_mfma_f32_16x16x32_bf16(pa1, bvq1, sacc[dt], 0, 0, 0);
    }
  }
  den += __shfl_xor(den, 16, 64);
  den += __shfl_xor(den, 32, 64);
  if (g == 0) denP[(size_t)(z * 8 + h) * NTOK + q0 + myrow] = den;
  const size_t base = (size_t)(z * 8 + h) * NTOK + q0 + w * 16;
#pragma unroll
  for (int dt = 0; dt < 5; ++dt)
#pragma unroll
    for (int r = 0; r < 4; ++r) {
      size_t o = (base + g * 4 + r) * 80 + dt * 16 + c;
      oP[o] = __half_as_ushort(__float2half(oacc[dt][r]));
      sP[o] = __half_as_ushort(__float2half(sacc[dt][r]));
    }
}

// ---------------- finalize: combine 8 z-slices + AdaIN epilogue -------------
__global__ __launch_bounds__(256) void k_fin(
    const unsigned short* __restrict__ oP, const unsigned short* __restrict__ sP,
    const float* __restrict__ denP, const float* __restrict__ qb,
    const float* __restrict__ mu, const float* __restrict__ rstd,
    const float* __restrict__ gate, float* __restrict__ Ob)
{
  int idx = blockIdx.x * 256 + threadIdx.x;
  int h = idx / (NTOK * 80);
  int rem = idx - h * (NTOK * 80);
  int n = rem / 80, d = rem - n * 80;
  float den = 0.f, o = 0.f, sq = 0.f;
#pragma unroll
  for (int zz = 0; zz < NZ; ++zz) {
    den += denP[(size_t)(zz * 8 + h) * NTOK + n];
    size_t p = ((size_t)(zz * 8 + h) * NTOK + n) * 80 + d;
    o += __half2float(__ushort_as_half(oP[p]));
    sq += __half2float(__ushort_as_half(sP[p]));
  }
  o /= den;
  sq /= den;
  float vstd = sqrtf(fmaxf(sq - o * o, 1e-5f));
  float g = tanhf(gate[0]);
  float qn = (qb[((size_t)h * NTOK + n) * 80 + d] - mu[h * DH + d]) * rstd[h * DH + d];
  Ob[(size_t)n * QD + h * DH + d] = fmaf(g * vstd, qn, o);
}

// ---------------- final projection: split-bf16 MFMA, out = Ob@Wo^T + bo -----
__global__ __launch_bounds__(256) void k_finalmm(
    const float* __restrict__ A, const float* __restrict__ W,
    const float* __restrict__ bias, float* __restrict__ out)
{
  const int n0 = blockIdx.y * 64, c0 = blockIdx.x * 64;
  const int tid = threadIdx.x;
  const int w = tid >> 6, l = tid & 63;
  const int cc = l & 15, g = l >> 4;

  __shared__ unsigned short sXh[64 * 72];
  __shared__ unsigned short sXl[64 * 72];
  __shared__ unsigned short sWh[64 * 72];
  __shared__ unsigned short sWl[64 * 72];

  f32x4 D[4];
#pragma unroll
  for (int ct = 0; ct < 4; ++ct) D[ct] = (f32x4){0.f, 0.f, 0.f, 0.f};

  for (int k0 = 0; k0 < QD; k0 += 64) {
    __syncthreads();
#pragma unroll
    for (int it = 0; it < 4; ++it) {
      int f = tid + it * 256;
      int row = f >> 4, col4 = f & 15;
      float4 xa = *(const float4*)(A + (size_t)(n0 + row) * QD + k0 + col4 * 4);
      float4 wa = *(const float4*)(W + (size_t)(c0 + row) * QD + k0 + col4 * 4);
      u16x4 xh, xl, wh, wl;
      float xv[4] = {xa.x, xa.y, xa.z, xa.w};
      float wv[4] = {wa.x, wa.y, wa.z, wa.w};
#pragma unroll
      for (int j = 0; j < 4; ++j) {
        unsigned short h1 = f2bf(xv[j]);
        xh[j] = h1; xl[j] = f2bf(xv[j] - bf2f(h1));
        unsigned short h2 = f2bf(wv[j]);
        wh[j] = h2; wl[j] = f2bf(wv[j] - bf2f(h2));
      }
      *(u16x4*)&sXh[row * 72 + col4 * 4] = xh;
      *(u16x4*)&sXl[row * 72 + col4 * 4] = xl;
      *(u16x4*)&sWh[row * 72 + col4 * 4] = wh;
      *(u16x4*)&sWl[row * 72 + col4 * 4] = wl;
    }
    __syncthreads();
    bf16x8 ah[2], al[2];
#pragma unroll
    for (int kc = 0; kc < 2; ++kc) {
      ah[kc] = *(const bf16x8*)&sXh[(w * 16 + cc) * 72 + kc * 32 + g * 8];
      al[kc] = *(const bf16x8*)&sXl[(w * 16 + cc) * 72 + kc * 32 + g * 8];
    }
#pragma unroll
    for (int ct = 0; ct < 4; ++ct) {
#pragma unroll
      for (int kc = 0; kc < 2; ++kc) {
        bf16x8 bh = *(const bf16x8*)&sWh[(ct * 16 + cc) * 72 + kc * 32 + g * 8];
        bf16x8 bl = *(const bf16x8*)&sWl[(ct * 16 + cc) * 72 + kc * 32 + g * 8];
        D[ct] = __builtin_amdgcn_mfma_f32_16x16x32_bf16(ah[kc], bh, D[ct], 0, 0, 0);
        D[ct] = __builtin_amdgcn_mfma_f32_16x16x32_bf16(ah[kc], bl, D[ct], 0, 0, 0);
        D[ct] = __builtin_amdgcn_mfma_f32_16x16x32_bf16(al[kc], bh, D[ct], 0, 0, 0);
      }
    }
  }
#pragma unroll
  for (int ct = 0; ct < 4; ++ct) {
#pragma unroll
    for (int r = 0; r < 4; ++r) {
      int n = n0 + w * 16 + g * 4 + r;
      int ccol = c0 + ct * 16 + cc;
      out[(size_t)n * QD + ccol] = D[ct][r] + bias[ccol];
    }
  }
}

extern "C" void kernel_launch(void* const* d_in, const int* in_sizes, int n_in,
                              void* d_out, int out_size, void* d_ws, size_t ws_size,
                              hipStream_t stream) {
  const float* x    = (const float*)d_in[0];
  const float* Qc   = (const float*)d_in[1];
  const float* Ks   = (const float*)d_in[2];
  const float* Vs   = (const float*)d_in[3];
  const float* Wq   = (const float*)d_in[4];
  const float* Wk   = (const float*)d_in[5];
  const float* Wv   = (const float*)d_in[6];
  const float* Wo   = (const float*)d_in[7];
  const float* bo   = (const float*)d_in[8];
  const float* gate = (const float*)d_in[9];
  float* out = (float*)d_out;
  float* w = (float*)d_ws;

  float* qb   = w + OFF_QB;
  float* Ob   = w + OFF_OB;
  unsigned short* qh_  = (unsigned short*)(w + OFF_QH);
  unsigned short* ql_  = (unsigned short*)(w + OFF_QL);
  unsigned short* kch_ = (unsigned short*)(w + OFF_KCH);
  unsigned short* Ksh  = (unsigned short*)(w + OFF_KSH);
  unsigned short* Ksl  = (unsigned short*)(w + OFF_KSL);
  unsigned short* VTc  = (unsigned short*)(w + OFF_VCT);
  unsigned short* VTqc = (unsigned short*)(w + OFF_VCQT);
  unsigned short* VTs  = (unsigned short*)(w + OFF_VST);
  unsigned short* VTqs = (unsigned short*)(w + OFF_VSQT);
  unsigned short* oP   = (unsigned short*)(w + OFF_OP);
  unsigned short* sP   = (unsigned short*)(w + OFF_SP);
  float* denP = w + OFF_DEN;
  float* mSz  = w + OFF_MSZ;
  float* lSz  = w + OFF_LSZ;
  float* mCz  = w + OFF_MCZ;
  float* lCz  = w + OFF_LCZ;
  float* M_   = w + OFF_M;
  float* lam_ = w + OFF_LAM;
  unsigned* thr_ = (unsigned*)(w + OFF_THR);
  float* mu   = w + OFF_MU;
  float* rstd = w + OFF_RSTD;
  unsigned short* S16  = (unsigned short*)(w + OFF_S16);
  unsigned short* Sc16 = (unsigned short*)(w + OFF_SC16);

  k_projmm<<<dim3(10, 32, 3), 256, 0, stream>>>(x, Wq, Wk, Wv, Qc, qb, qh_, ql_, kch_, VTc, VTqc);
  k_cvt<<<dim3(32, 8), 256, 0, stream>>>(Ks, Vs, Ksh, Ksl, VTs, VTqs, qh_, ql_, kch_);
  k_qstats<<<dim3(640), 128, 0, stream>>>(qb, mu, rstd);
  k_passA<<<dim3(2048), 256, 0, stream>>>(qh_, ql_, Ksh, Ksl, kch_, S16, Sc16, mSz, lSz, mCz, lCz);
  k_gate<<<dim3(8), 256, 0, stream>>>(mSz, lSz, mCz, lCz, M_, lam_);
  k_topk<<<dim3(256, 8), 512, 0, stream>>>(S16, thr_);
  k_passB<<<dim3(2048), 256, 0, stream>>>(VTs, VTqs, VTc, VTqc, S16, Sc16, M_, lam_, thr_, oP, sP, denP);
  k_fin<<<dim3(5120), 256, 0, stream>>>(oP, sP, denP, qb, mu, rstd, gate, Ob);
  k_finalmm<<<dim3(10, 32), 256, 0, stream>>>(Ob, Wo, bo, out);
}

// Round 12
// 295.039 us; speedup vs baseline: 1.0097x; 1.0097x over previous
//
#include <hip/hip_runtime.h>
#include <hip/hip_fp16.h>
#include <math.h>

#define NH 8
#define DH 80
#define NTOK 2048
#define QD 640
#define SCALE_F 0.11180339887498949f
#define TSCALE_F (1.2f * SCALE_F)
#define GAMMA_F 0.3f
#define LMAX_F 2.5f
#define TOPKN 128
#define NZA 8   // passA z-split (grid 2048)
#define NZB 4   // passB z-split (grid 1024)

typedef __attribute__((ext_vector_type(8))) short bf16x8;
typedef __attribute__((ext_vector_type(4))) float f32x4;
typedef __attribute__((ext_vector_type(4))) unsigned short u16x4;

// ---- ws float offsets ----
#define OFF_QB   0u            // f32 [8][2048][80]
#define OFF_OB   1310720u      // f32 [2048][640]
#define OFF_QH   2621440u      // bf16 [8][2048][96]
#define OFF_QL   3407872u
#define OFF_KCH  4194304u
#define OFF_KSH  4980736u
#define OFF_KSL  5767168u
#define OFF_VCT  6553600u      // bf16 VT_c  [8][80][2048]
#define OFF_VCQT 7208960u
#define OFF_VST  7864320u
#define OFF_VSQT 8519680u
#define OFF_OP   9175040u      // f32 [4][8][2048][80] = 5242880
#define OFF_SP   14417920u     // f32 [4][8][2048][80]
#define OFF_DEN  19660800u     // f32 [4][8][2048]
#define OFF_MSZ  19791872u     // f32 [8][8][2048] each
#define OFF_LSZ  19922944u
#define OFF_MCZ  20054016u
#define OFF_LCZ  20185088u
#define OFF_M    20316160u     // f32 [8][2048]
#define OFF_LAM  20332544u
#define OFF_THR  20334592u
#define OFF_MU   20350976u
#define OFF_RSTD 20351616u
#define OFF_S16  20352256u     // fp16 style   S [8][2048][2048]
#define OFF_SC16 37129472u     // fp16 content S [8][2048][2048]

static __device__ __forceinline__ unsigned short f2bf(float f) {
  unsigned u = __float_as_uint(f);
  return (unsigned short)((u + 0x7FFFu + ((u >> 16) & 1u)) >> 16);
}
static __device__ __forceinline__ float bf2f(unsigned short s) {
  return __uint_as_float(((unsigned)s) << 16);
}
static __device__ __forceinline__ unsigned sk16(unsigned u) {
  return (u & 0x8000u) ? (~u & 0xFFFFu) : (u | 0x8000u);
}

// ---------------- split-bf16 MFMA projection GEMM ---------------------------
__global__ __launch_bounds__(256) void k_projmm(
    const float* __restrict__ x, const float* __restrict__ Wq,
    const float* __restrict__ Wk, const float* __restrict__ Wv,
    const float* __restrict__ Qc, float* __restrict__ qb,
    unsigned short* __restrict__ qh_, unsigned short* __restrict__ ql_,
    unsigned short* __restrict__ kch_,
    unsigned short* __restrict__ vct_, unsigned short* __restrict__ vcqt_)
{
  const float* W = (blockIdx.z == 0) ? Wq : ((blockIdx.z == 1) ? Wk : Wv);
  const int n0 = blockIdx.y * 64, c0 = blockIdx.x * 64;
  const int tid = threadIdx.x;
  const int w = tid >> 6, l = tid & 63;
  const int cc = l & 15, g = l >> 4;
  const bool full3 = (blockIdx.z == 0);

  __shared__ unsigned short sXh[64 * 72];
  __shared__ unsigned short sXl[64 * 72];
  __shared__ unsigned short sWh[64 * 72];
  __shared__ unsigned short sWl[64 * 72];

  f32x4 D[4];
#pragma unroll
  for (int ct = 0; ct < 4; ++ct) D[ct] = (f32x4){0.f, 0.f, 0.f, 0.f};

  for (int k0 = 0; k0 < QD; k0 += 64) {
    __syncthreads();
#pragma unroll
    for (int it = 0; it < 4; ++it) {
      int f = tid + it * 256;
      int row = f >> 4, col4 = f & 15;
      float4 xa = *(const float4*)(x + (size_t)(n0 + row) * QD + k0 + col4 * 4);
      float4 wa = *(const float4*)(W + (size_t)(c0 + row) * QD + k0 + col4 * 4);
      u16x4 xh, xl, wh, wl;
      float xv[4] = {xa.x, xa.y, xa.z, xa.w};
      float wv[4] = {wa.x, wa.y, wa.z, wa.w};
#pragma unroll
      for (int j = 0; j < 4; ++j) {
        unsigned short h1 = f2bf(xv[j]);
        xh[j] = h1; xl[j] = f2bf(xv[j] - bf2f(h1));
        unsigned short h2 = f2bf(wv[j]);
        wh[j] = h2; wl[j] = f2bf(wv[j] - bf2f(h2));
      }
      *(u16x4*)&sXh[row * 72 + col4 * 4] = xh;
      *(u16x4*)&sXl[row * 72 + col4 * 4] = xl;
      *(u16x4*)&sWh[row * 72 + col4 * 4] = wh;
      *(u16x4*)&sWl[row * 72 + col4 * 4] = wl;
    }
    __syncthreads();
    bf16x8 ah[2], al[2];
#pragma unroll
    for (int kc = 0; kc < 2; ++kc) {
      ah[kc] = *(const bf16x8*)&sXh[(w * 16 + cc) * 72 + kc * 32 + g * 8];
      al[kc] = *(const bf16x8*)&sXl[(w * 16 + cc) * 72 + kc * 32 + g * 8];
    }
#pragma unroll
    for (int ct = 0; ct < 4; ++ct) {
#pragma unroll
      for (int kc = 0; kc < 2; ++kc) {
        bf16x8 bh = *(const bf16x8*)&sWh[(ct * 16 + cc) * 72 + kc * 32 + g * 8];
        bf16x8 bl = *(const bf16x8*)&sWl[(ct * 16 + cc) * 72 + kc * 32 + g * 8];
        D[ct] = __builtin_amdgcn_mfma_f32_16x16x32_bf16(ah[kc], bh, D[ct], 0, 0, 0);
        D[ct] = __builtin_amdgcn_mfma_f32_16x16x32_bf16(ah[kc], bl, D[ct], 0, 0, 0);
        if (full3)
          D[ct] = __builtin_amdgcn_mfma_f32_16x16x32_bf16(al[kc], bh, D[ct], 0, 0, 0);
      }
    }
  }
#pragma unroll
  for (int ct = 0; ct < 4; ++ct) {
#pragma unroll
    for (int r = 0; r < 4; ++r) {
      int n = n0 + w * 16 + g * 4 + r;
      int ccol = c0 + ct * 16 + cc;
      int h = ccol / DH, d = ccol - h * DH;
      size_t i80 = ((size_t)h * NTOK + n) * 80 + d;
      size_t i96 = ((size_t)h * NTOK + n) * 96 + d;
      float val = D[ct][r];
      if (blockIdx.z == 0) {
        val = GAMMA_F * Qc[i80] + (1.f - GAMMA_F) * val;
        qb[i80] = val;
        unsigned short hs = f2bf(val);
        qh_[i96] = hs;
        ql_[i96] = f2bf(val - bf2f(hs));
      } else if (blockIdx.z == 1) {
        kch_[i96] = f2bf(val);
      } else {
        size_t iT = (((size_t)h * 80 + d) << 11) + n;
        vct_[iT]  = f2bf(val);
        vcqt_[iT] = f2bf(val * val);
      }
    }
  }
}

// ---------------- style inputs: K split + pads; V transposed to VT ----------
__global__ __launch_bounds__(256) void k_cvt(
    const float* __restrict__ Ks, const float* __restrict__ Vs,
    unsigned short* __restrict__ Ksh, unsigned short* __restrict__ Ksl,
    unsigned short* __restrict__ VTs, unsigned short* __restrict__ VTqs,
    unsigned short* __restrict__ qh_, unsigned short* __restrict__ ql_,
    unsigned short* __restrict__ kch_)
{
  const int h = blockIdx.y;
  const int n0 = blockIdx.x * 64;
  const int tid = threadIdx.x;
  __shared__ unsigned short sVT[80 * 68];
  __shared__ unsigned short sVQ[80 * 68];

  for (int f = tid; f < 1280; f += 256) {
    int rr = f / 20, dc = f % 20;
    size_t i80 = ((size_t)h * NTOK + n0 + rr) * 80 + dc * 4;
    size_t i96 = ((size_t)h * NTOK + n0 + rr) * 96 + dc * 4;
    float4 kv = *(const float4*)(Ks + i80);
    float kvv[4] = {kv.x, kv.y, kv.z, kv.w};
    u16x4 kh, kl;
#pragma unroll
    for (int j = 0; j < 4; ++j) {
      unsigned short hs = f2bf(kvv[j]);
      kh[j] = hs; kl[j] = f2bf(kvv[j] - bf2f(hs));
    }
    *(u16x4*)(Ksh + i96) = kh;
    *(u16x4*)(Ksl + i96) = kl;
    float4 vv = *(const float4*)(Vs + i80);
    float vvv[4] = {vv.x, vv.y, vv.z, vv.w};
#pragma unroll
    for (int j = 0; j < 4; ++j) {
      int d = dc * 4 + j;
      sVT[d * 68 + rr] = f2bf(vvv[j]);
      sVQ[d * 68 + rr] = f2bf(vvv[j] * vvv[j]);
    }
  }
  for (int f = tid; f < 1024; f += 256) {
    int rr = f >> 4, dcol = 80 + (f & 15);
    size_t i96 = ((size_t)h * NTOK + n0 + rr) * 96 + dcol;
    Ksh[i96] = 0; Ksl[i96] = 0; qh_[i96] = 0; ql_[i96] = 0; kch_[i96] = 0;
  }
  __syncthreads();
  for (int f = tid; f < 640; f += 256) {
    int d = f >> 3, kp8 = f & 7;
    size_t iT = (((size_t)h * 80 + d) << 11) + n0 + kp8 * 8;
    *(bf16x8*)(VTs + iT)  = *(const bf16x8*)&sVT[d * 68 + kp8 * 8];
    *(bf16x8*)(VTqs + iT) = *(const bf16x8*)&sVQ[d * 68 + kp8 * 8];
  }
}

// ---------------- per-(h,d) mean / rstd of q over tokens --------------------
__global__ __launch_bounds__(128) void k_qstats(
    const float* __restrict__ qb, float* __restrict__ mu, float* __restrict__ rstd)
{
  const int h = blockIdx.x / DH, d = blockIdx.x % DH;
  const int tid = threadIdx.x;
  float s = 0.f, s2 = 0.f;
  for (int n = tid; n < NTOK; n += 128) {
    float v = qb[((size_t)h * NTOK + n) * 80 + d];
    s += v; s2 = fmaf(v, v, s2);
  }
#pragma unroll
  for (int off = 32; off; off >>= 1) { s += __shfl_xor(s, off, 64); s2 += __shfl_xor(s2, off, 64); }
  __shared__ float sh[4];
  if ((tid & 63) == 0) { sh[(tid >> 6) * 2] = s; sh[(tid >> 6) * 2 + 1] = s2; }
  __syncthreads();
  if (tid == 0) {
    float S = sh[0] + sh[2], S2 = sh[1] + sh[3];
    float mval = S * (1.f / NTOK);
    float var = S2 * (1.f / NTOK) - mval * mval;
    mu[h * DH + d] = mval;
    rstd[h * DH + d] = rsqrtf(var + 1e-5f);
  }
}

// ---------------- pass A (z=8, XCD-swizzled): logits -> fp16 S/Sc; LSE ------
__global__ __launch_bounds__(256) void k_passA(
    const unsigned short* __restrict__ qh_, const unsigned short* __restrict__ ql_,
    const unsigned short* __restrict__ Ksh, const unsigned short* __restrict__ Ksl,
    const unsigned short* __restrict__ kch_,
    unsigned short* __restrict__ S16, unsigned short* __restrict__ Sc16,
    float* __restrict__ mSz, float* __restrict__ lSz,
    float* __restrict__ mCz, float* __restrict__ lCz)
{
  const int bid = blockIdx.x;
  const int swz = (bid & 7) * 256 + (bid >> 3);   // 2048 % 8 == 0: bijective
  const int q0 = (swz & 31) * 64;
  const int h  = (swz >> 5) & 7;
  const int z  = swz >> 8;                        // 0..7
  const int tid = threadIdx.x;
  const int w = tid >> 6, l = tid & 63;
  const int c = l & 15, g = l >> 4;

  __shared__ unsigned short sKh[64 * 104];
  __shared__ unsigned short sKl[64 * 104];

  bf16x8 qhf[3], qlf[3];
  {
    const size_t qrow = ((size_t)h * NTOK + q0 + w * 16 + c) * 96;
#pragma unroll
    for (int kc = 0; kc < 3; ++kc) {
      qhf[kc] = *(const bf16x8*)(qh_ + qrow + kc * 32 + g * 8);
      qlf[kc] = *(const bf16x8*)(ql_ + qrow + kc * 32 + g * 8);
    }
  }
  float m[4], lse[4], mc[4], lc[4];
#pragma unroll
  for (int r = 0; r < 4; ++r) { m[r] = -INFINITY; lse[r] = 0.f; mc[r] = -INFINITY; lc[r] = 0.f; }

  for (int t = 0; t < 4; ++t) {
    const size_t kbase = ((size_t)h * NTOK + z * 256 + t * 64) * 96;
    __syncthreads();
    for (int f = tid; f < 768; f += 256) {
      int row = f / 12, ch = f % 12;
      *(bf16x8*)(sKh + row * 104 + ch * 8) = *(const bf16x8*)(Ksh + kbase + row * 96 + ch * 8);
      *(bf16x8*)(sKl + row * 104 + ch * 8) = *(const bf16x8*)(Ksl + kbase + row * 96 + ch * 8);
    }
    __syncthreads();
#pragma unroll
    for (int ct = 0; ct < 4; ++ct) {
      f32x4 D = {0.f, 0.f, 0.f, 0.f};
      const int krow = (ct * 16 + c) * 104 + g * 8;
#pragma unroll
      for (int kc = 0; kc < 3; ++kc) {
        bf16x8 bh = *(const bf16x8*)(sKh + krow + kc * 32);
        D = __builtin_amdgcn_mfma_f32_16x16x32_bf16(qhf[kc], bh, D, 0, 0, 0);
      }
#pragma unroll
      for (int kc = 0; kc < 3; ++kc) {
        bf16x8 bl = *(const bf16x8*)(sKl + krow + kc * 32);
        D = __builtin_amdgcn_mfma_f32_16x16x32_bf16(qhf[kc], bl, D, 0, 0, 0);
      }
#pragma unroll
      for (int kc = 0; kc < 3; ++kc) {
        bf16x8 bh = *(const bf16x8*)(sKh + krow + kc * 32);
        D = __builtin_amdgcn_mfma_f32_16x16x32_bf16(qlf[kc], bh, D, 0, 0, 0);
      }
#pragma unroll
      for (int r = 0; r < 4; ++r) {
        float s = D[r] * TSCALE_F;
        S16[((size_t)h * NTOK + q0 + w * 16 + g * 4 + r) * 2048 + z * 256 + t * 64 + ct * 16 + c] =
            __half_as_ushort(__float2half(s));
        lse[r] += __expf(s);
        m[r] = fmaxf(m[r], s);
      }
    }
  }
  for (int t = 0; t < 4; ++t) {
    const size_t kbase = ((size_t)h * NTOK + z * 256 + t * 64) * 96;
    __syncthreads();
    for (int f = tid; f < 768; f += 256) {
      int row = f / 12, ch = f % 12;
      *(bf16x8*)(sKh + row * 104 + ch * 8) = *(const bf16x8*)(kch_ + kbase + row * 96 + ch * 8);
    }
    __syncthreads();
#pragma unroll
    for (int ct = 0; ct < 4; ++ct) {
      f32x4 D = {0.f, 0.f, 0.f, 0.f};
      const int krow = (ct * 16 + c) * 104 + g * 8;
#pragma unroll
      for (int kc = 0; kc < 3; ++kc) {
        bf16x8 bh = *(const bf16x8*)(sKh + krow + kc * 32);
        D = __builtin_amdgcn_mfma_f32_16x16x32_bf16(qhf[kc], bh, D, 0, 0, 0);
      }
#pragma unroll
      for (int r = 0; r < 4; ++r) {
        float s = D[r] * SCALE_F;
        Sc16[((size_t)h * NTOK + q0 + w * 16 + g * 4 + r) * 2048 + z * 256 + t * 64 + ct * 16 + c] =
            __half_as_ushort(__float2half(s));
        lc[r] += __expf(s);
        mc[r] = fmaxf(mc[r], s);
      }
    }
  }
#pragma unroll
  for (int off = 1; off < 16; off <<= 1) {
#pragma unroll
    for (int r = 0; r < 4; ++r) {
      lse[r] += __shfl_xor(lse[r], off, 64);
      m[r] = fmaxf(m[r], __shfl_xor(m[r], off, 64));
      lc[r] += __shfl_xor(lc[r], off, 64);
      mc[r] = fmaxf(mc[r], __shfl_xor(mc[r], off, 64));
    }
  }
  if (c == 0) {
    size_t base = (size_t)(z * 8 + h) * NTOK + q0 + w * 16 + g * 4;
#pragma unroll
    for (int r = 0; r < 4; ++r) {
      mSz[base + r] = m[r]; lSz[base + r] = lse[r];
      mCz[base + r] = mc[r]; lCz[base + r] = lc[r];
    }
  }
}

// ---------------- gate: combine 8 z-slices (fixed-base sums), lambda, M -----
__global__ __launch_bounds__(256) void k_gate(
    const float* __restrict__ mSz, const float* __restrict__ lSz,
    const float* __restrict__ mCz, const float* __restrict__ lCz,
    float* __restrict__ M_, float* __restrict__ lam_)
{
  int n = blockIdx.x * 256 + threadIdx.x;
  if (n >= NTOK) return;
  float msf[NH], mcf[NH], sum = 0.f;
#pragma unroll
  for (int h = 0; h < NH; ++h) {
    float mm = -INFINITY, cm = -INFINITY, ls = 0.f, lcs = 0.f;
#pragma unroll
    for (int zz = 0; zz < NZA; ++zz) {
      mm = fmaxf(mm, mSz[(size_t)(zz * 8 + h) * NTOK + n]);
      cm = fmaxf(cm, mCz[(size_t)(zz * 8 + h) * NTOK + n]);
      ls  += lSz[(size_t)(zz * 8 + h) * NTOK + n];
      lcs += lCz[(size_t)(zz * 8 + h) * NTOK + n];
    }
    float lse_s = __logf(ls);
    float lse_c = __logf(lcs);
    msf[h] = mm; mcf[h] = cm;
    sum += fminf(fmaxf(lse_s - lse_c, -20.f), 20.f);
  }
  float lam = 1.f + (LMAX_F - 1.f) * (1.f / (1.f + __expf(-sum * (1.f / NH))));
  lam_[n] = lam;
#pragma unroll
  for (int h = 0; h < NH; ++h)
    M_[h * NTOK + n] = fmaxf(lam * msf[h], mcf[h]);
}

// ---------------- top-k threshold: 16-bit ballot bisection on fp16 S --------
__global__ __launch_bounds__(512) void k_topk(const unsigned short* __restrict__ S16,
                                              unsigned* __restrict__ thr_)
{
  const int h = blockIdx.y;
  const int n = blockIdx.x * 8 + (threadIdx.x >> 6);
  const int l = threadIdx.x & 63;
  const unsigned short* Srow = S16 + ((size_t)h * NTOK + n) * 2048;
  unsigned kv[32];
#pragma unroll
  for (int t = 0; t < 4; ++t) {
    uint4 v = ((const uint4*)Srow)[t * 64 + l];
    unsigned dw[4] = {v.x, v.y, v.z, v.w};
#pragma unroll
    for (int i = 0; i < 8; ++i) {
      unsigned u = (dw[i >> 1] >> ((i & 1) * 16)) & 0xFFFFu;
      kv[t * 8 + i] = sk16(u);
    }
  }
  unsigned klo = 0u, khi = 65536u;
  for (int it = 0; it < 16; ++it) {
    unsigned mid = (klo + khi) >> 1;
    int cnt = 0;
#pragma unroll
    for (int t = 0; t < 32; ++t)
      cnt += __popcll(__ballot(kv[t] >= mid));
    if (cnt == TOPKN) { klo = mid; break; }
    if (cnt > TOPKN) klo = mid; else khi = mid;
    if (khi - klo <= 1u) break;
  }
  if (l == 0) thr_[h * NTOK + n] = klo;
}

// ---------------- pass B (z=4): pure PV, f32 partial outputs ----------------
__global__ __launch_bounds__(256) void k_passB(
    const unsigned short* __restrict__ VTs, const unsigned short* __restrict__ VTqs,
    const unsigned short* __restrict__ VTc, const unsigned short* __restrict__ VTqc,
    const unsigned short* __restrict__ S16, const unsigned short* __restrict__ Sc16,
    const float* __restrict__ M_, const float* __restrict__ lam_,
    const unsigned* __restrict__ thr_,
    float* __restrict__ oP, float* __restrict__ sP, float* __restrict__ denP)
{
  const int bid = blockIdx.x;
  const int swz = (bid & 7) * 128 + (bid >> 3);   // 1024 % 8 == 0: bijective
  const int q0 = (swz & 31) * 64;
  const int h  = (swz >> 5) & 7;
  const int z  = swz >> 8;                        // 0..3
  const int tid = threadIdx.x;
  const int w = tid >> 6, l = tid & 63;
  const int c = l & 15, g = l >> 4;

  __shared__ unsigned short vT[80 * 72];
  __shared__ unsigned short vqT[80 * 72];

  const int myrow = w * 16 + c;
  const float myM = M_[h * NTOK + q0 + myrow];
  const float myLam = lam_[q0 + myrow];
  const unsigned myThr = thr_[h * NTOK + q0 + myrow];

  const size_t srow = ((size_t)h * NTOK + q0 + myrow) * 2048 + g * 8;
  const int d0 = tid >> 3, kp8 = tid & 7;
  const size_t vr0 = (((size_t)h * 80 + d0) << 11) + kp8 * 8;
  const size_t vr1 = (((size_t)h * 80 + d0 + 32) << 11) + kp8 * 8;
  const size_t vr2 = (((size_t)h * 80 + d0 + 64) << 11) + kp8 * 8;
  const bool third = (tid < 128);

  f32x4 oacc[5], sacc[5];
#pragma unroll
  for (int dt = 0; dt < 5; ++dt) { oacc[dt] = (f32x4){0.f,0.f,0.f,0.f}; sacc[dt] = (f32x4){0.f,0.f,0.f,0.f}; }
  float den = 0.f;

  for (int t = 0; t < 16; ++t) {
    const bool style = (t < 8);
    const int k0 = z * 512 + (t & 7) * 64;
    const unsigned short* Sp = style ? S16 : Sc16;
    const unsigned short* Vp = style ? VTs : VTc;
    const unsigned short* Vq = style ? VTqs : VTqc;
    uint4 s0 = *(const uint4*)(Sp + srow + k0);
    uint4 s1 = *(const uint4*)(Sp + srow + k0 + 32);
    bf16x8 v0 = *(const bf16x8*)(Vp + vr0 + k0);
    bf16x8 v1 = *(const bf16x8*)(Vp + vr1 + k0);
    bf16x8 u0 = *(const bf16x8*)(Vq + vr0 + k0);
    bf16x8 u1 = *(const bf16x8*)(Vq + vr1 + k0);
    bf16x8 v2, u2;
    if (third) {
      v2 = *(const bf16x8*)(Vp + vr2 + k0);
      u2 = *(const bf16x8*)(Vq + vr2 + k0);
    }
    __syncthreads();
    *(bf16x8*)&vT[d0 * 72 + kp8 * 8] = v0;
    *(bf16x8*)&vqT[d0 * 72 + kp8 * 8] = u0;
    *(bf16x8*)&vT[(d0 + 32) * 72 + kp8 * 8] = v1;
    *(bf16x8*)&vqT[(d0 + 32) * 72 + kp8 * 8] = u1;
    if (third) {
      *(bf16x8*)&vT[(d0 + 64) * 72 + kp8 * 8] = v2;
      *(bf16x8*)&vqT[(d0 + 64) * 72 + kp8 * 8] = u2;
    }
    __syncthreads();
    bf16x8 pa0, pa1;
    {
      unsigned dw0[4] = {s0.x, s0.y, s0.z, s0.w};
      unsigned dw1[4] = {s1.x, s1.y, s1.z, s1.w};
#pragma unroll
      for (int i = 0; i < 8; ++i) {
        unsigned ua = (dw0[i >> 1] >> ((i & 1) * 16)) & 0xFFFFu;
        float sa = __half2float(__ushort_as_half((unsigned short)ua));
        float wa = style ? ((sk16(ua) >= myThr) ? __expf(myLam * sa - myM) : 0.f)
                         : __expf(sa - myM);
        den += wa;
        pa0[i] = (short)f2bf(wa);
        unsigned ub = (dw1[i >> 1] >> ((i & 1) * 16)) & 0xFFFFu;
        float sb = __half2float(__ushort_as_half((unsigned short)ub));
        float wb = style ? ((sk16(ub) >= myThr) ? __expf(myLam * sb - myM) : 0.f)
                         : __expf(sb - myM);
        den += wb;
        pa1[i] = (short)f2bf(wb);
      }
    }
#pragma unroll
    for (int dt = 0; dt < 5; ++dt) {
      bf16x8 bv0  = *(const bf16x8*)&vT[(dt * 16 + c) * 72 + g * 8];
      bf16x8 bvq0 = *(const bf16x8*)&vqT[(dt * 16 + c) * 72 + g * 8];
      bf16x8 bv1  = *(const bf16x8*)&vT[(dt * 16 + c) * 72 + 32 + g * 8];
      bf16x8 bvq1 = *(const bf16x8*)&vqT[(dt * 16 + c) * 72 + 32 + g * 8];
      oacc[dt] = __builtin_amdgcn_mfma_f32_16x16x32_bf16(pa0, bv0, oacc[dt], 0, 0, 0);
      sacc[dt] = __builtin_amdgcn_mfma_f32_16x16x32_bf16(pa0, bvq0, sacc[dt], 0, 0, 0);
      oacc[dt] = __builtin_amdgcn_mfma_f32_16x16x32_bf16(pa1, bv1, oacc[dt], 0, 0, 0);
      sacc[dt] = __builtin_amdgcn_mfma_f32_16x16x32_bf16(pa1, bvq1, sacc[dt], 0, 0, 0);
    }
  }
  den += __shfl_xor(den, 16, 64);
  den += __shfl_xor(den, 32, 64);
  if (g == 0) denP[(size_t)(z * 8 + h) * NTOK + q0 + myrow] = den;
  const size_t base = (size_t)(z * 8 + h) * NTOK + q0 + w * 16;
#pragma unroll
  for (int dt = 0; dt < 5; ++dt)
#pragma unroll
    for (int r = 0; r < 4; ++r) {
      size_t o = (base + g * 4 + r) * 80 + dt * 16 + c;
      oP[o] = oacc[dt][r];
      sP[o] = sacc[dt][r];
    }
}

// ---------------- finalize: combine 4 z-slices + AdaIN epilogue -------------
__global__ __launch_bounds__(256) void k_fin(
    const float* __restrict__ oP, const float* __restrict__ sP,
    const float* __restrict__ denP, const float* __restrict__ qb,
    const float* __restrict__ mu, const float* __restrict__ rstd,
    const float* __restrict__ gate, float* __restrict__ Ob)
{
  int idx = blockIdx.x * 256 + threadIdx.x;
  int h = idx / (NTOK * 80);
  int rem = idx - h * (NTOK * 80);
  int n = rem / 80, d = rem - n * 80;
  float den = 0.f, o = 0.f, sq = 0.f;
#pragma unroll
  for (int zz = 0; zz < NZB; ++zz) {
    den += denP[(size_t)(zz * 8 + h) * NTOK + n];
    size_t p = ((size_t)(zz * 8 + h) * NTOK + n) * 80 + d;
    o += oP[p];
    sq += sP[p];
  }
  o /= den;
  sq /= den;
  float vstd = sqrtf(fmaxf(sq - o * o, 1e-5f));
  float g = tanhf(gate[0]);
  float qn = (qb[((size_t)h * NTOK + n) * 80 + d] - mu[h * DH + d]) * rstd[h * DH + d];
  Ob[(size_t)n * QD + h * DH + d] = fmaf(g * vstd, qn, o);
}

// ---------------- final projection: split-bf16 MFMA, out = Ob@Wo^T + bo -----
__global__ __launch_bounds__(256) void k_finalmm(
    const float* __restrict__ A, const float* __restrict__ W,
    const float* __restrict__ bias, float* __restrict__ out)
{
  const int n0 = blockIdx.y * 64, c0 = blockIdx.x * 64;
  const int tid = threadIdx.x;
  const int w = tid >> 6, l = tid & 63;
  const int cc = l & 15, g = l >> 4;

  __shared__ unsigned short sXh[64 * 72];
  __shared__ unsigned short sXl[64 * 72];
  __shared__ unsigned short sWh[64 * 72];
  __shared__ unsigned short sWl[64 * 72];

  f32x4 D[4];
#pragma unroll
  for (int ct = 0; ct < 4; ++ct) D[ct] = (f32x4){0.f, 0.f, 0.f, 0.f};

  for (int k0 = 0; k0 < QD; k0 += 64) {
    __syncthreads();
#pragma unroll
    for (int it = 0; it < 4; ++it) {
      int f = tid + it * 256;
      int row = f >> 4, col4 = f & 15;
      float4 xa = *(const float4*)(A + (size_t)(n0 + row) * QD + k0 + col4 * 4);
      float4 wa = *(const float4*)(W + (size_t)(c0 + row) * QD + k0 + col4 * 4);
      u16x4 xh, xl, wh, wl;
      float xv[4] = {xa.x, xa.y, xa.z, xa.w};
      float wv[4] = {wa.x, wa.y, wa.z, wa.w};
#pragma unroll
      for (int j = 0; j < 4; ++j) {
        unsigned short h1 = f2bf(xv[j]);
        xh[j] = h1; xl[j] = f2bf(xv[j] - bf2f(h1));
        unsigned short h2 = f2bf(wv[j]);
        wh[j] = h2; wl[j] = f2bf(wv[j] - bf2f(h2));
      }
      *(u16x4*)&sXh[row * 72 + col4 * 4] = xh;
      *(u16x4*)&sXl[row * 72 + col4 * 4] = xl;
      *(u16x4*)&sWh[row * 72 + col4 * 4] = wh;
      *(u16x4*)&sWl[row * 72 + col4 * 4] = wl;
    }
    __syncthreads();
    bf16x8 ah[2], al[2];
#pragma unroll
    for (int kc = 0; kc < 2; ++kc) {
      ah[kc] = *(const bf16x8*)&sXh[(w * 16 + cc) * 72 + kc * 32 + g * 8];
      al[kc] = *(const bf16x8*)&sXl[(w * 16 + cc) * 72 + kc * 32 + g * 8];
    }
#pragma unroll
    for (int ct = 0; ct < 4; ++ct) {
#pragma unroll
      for (int kc = 0; kc < 2; ++kc) {
        bf16x8 bh = *(const bf16x8*)&sWh[(ct * 16 + cc) * 72 + kc * 32 + g * 8];
        bf16x8 bl = *(const bf16x8*)&sWl[(ct * 16 + cc) * 72 + kc * 32 + g * 8];
        D[ct] = __builtin_amdgcn_mfma_f32_16x16x32_bf16(ah[kc], bh, D[ct], 0, 0, 0);
        D[ct] = __builtin_amdgcn_mfma_f32_16x16x32_bf16(ah[kc], bl, D[ct], 0, 0, 0);
        D[ct] = __builtin_amdgcn_mfma_f32_16x16x32_bf16(al[kc], bh, D[ct], 0, 0, 0);
      }
    }
  }
#pragma unroll
  for (int ct = 0; ct < 4; ++ct) {
#pragma unroll
    for (int r = 0; r < 4; ++r) {
      int n = n0 + w * 16 + g * 4 + r;
      int ccol = c0 + ct * 16 + cc;
      out[(size_t)n * QD + ccol] = D[ct][r] + bias[ccol];
    }
  }
}

extern "C" void kernel_launch(void* const* d_in, const int* in_sizes, int n_in,
                              void* d_out, int out_size, void* d_ws, size_t ws_size,
                              hipStream_t stream) {
  const float* x    = (const float*)d_in[0];
  const float* Qc   = (const float*)d_in[1];
  const float* Ks   = (const float*)d_in[2];
  const float* Vs   = (const float*)d_in[3];
  const float* Wq   = (const float*)d_in[4];
  const float* Wk   = (const float*)d_in[5];
  const float* Wv   = (const float*)d_in[6];
  const float* Wo   = (const float*)d_in[7];
  const float* bo   = (const float*)d_in[8];
  const float* gate = (const float*)d_in[9];
  float* out = (float*)d_out;
  float* w = (float*)d_ws;

  float* qb   = w + OFF_QB;
  float* Ob   = w + OFF_OB;
  unsigned short* qh_  = (unsigned short*)(w + OFF_QH);
  unsigned short* ql_  = (unsigned short*)(w + OFF_QL);
  unsigned short* kch_ = (unsigned short*)(w + OFF_KCH);
  unsigned short* Ksh  = (unsigned short*)(w + OFF_KSH);
  unsigned short* Ksl  = (unsigned short*)(w + OFF_KSL);
  unsigned short* VTc  = (unsigned short*)(w + OFF_VCT);
  unsigned short* VTqc = (unsigned short*)(w + OFF_VCQT);
  unsigned short* VTs  = (unsigned short*)(w + OFF_VST);
  unsigned short* VTqs = (unsigned short*)(w + OFF_VSQT);
  float* oP   = w + OFF_OP;
  float* sP   = w + OFF_SP;
  float* denP = w + OFF_DEN;
  float* mSz  = w + OFF_MSZ;
  float* lSz  = w + OFF_LSZ;
  float* mCz  = w + OFF_MCZ;
  float* lCz  = w + OFF_LCZ;
  float* M_   = w + OFF_M;
  float* lam_ = w + OFF_LAM;
  unsigned* thr_ = (unsigned*)(w + OFF_THR);
  float* mu   = w + OFF_MU;
  float* rstd = w + OFF_RSTD;
  unsigned short* S16  = (unsigned short*)(w + OFF_S16);
  unsigned short* Sc16 = (unsigned short*)(w + OFF_SC16);

  k_projmm<<<dim3(10, 32, 3), 256, 0, stream>>>(x, Wq, Wk, Wv, Qc, qb, qh_, ql_, kch_, VTc, VTqc);
  k_cvt<<<dim3(32, 8), 256, 0, stream>>>(Ks, Vs, Ksh, Ksl, VTs, VTqs, qh_, ql_, kch_);
  k_qstats<<<dim3(640), 128, 0, stream>>>(qb, mu, rstd);
  k_passA<<<dim3(2048), 256, 0, stream>>>(qh_, ql_, Ksh, Ksl, kch_, S16, Sc16, mSz, lSz, mCz, lCz);
  k_gate<<<dim3(8), 256, 0, stream>>>(mSz, lSz, mCz, lCz, M_, lam_);
  k_topk<<<dim3(256, 8), 512, 0, stream>>>(S16, thr_);
  k_passB<<<dim3(1024), 256, 0, stream>>>(VTs, VTqs, VTc, VTqc, S16, Sc16, M_, lam_, thr_, oP, sP, denP);
  k_fin<<<dim3(5120), 256, 0, stream>>>(oP, sP, denP, qb, mu, rstd, gate, Ob);
  k_finalmm<<<dim3(10, 32), 256, 0, stream>>>(Ob, Wo, bo, out);
}

// Round 13
// 251.670 us; speedup vs baseline: 1.1837x; 1.1723x over previous
//
#include <hip/hip_runtime.h>
#include <hip/hip_fp16.h>
#include <math.h>

#define NH 8
#define DH 80
#define NTOK 2048
#define QD 640
#define SCALE_F 0.11180339887498949f
#define TSCALE_F (1.2f * SCALE_F)
#define GAMMA_F 0.3f
#define LMAX_F 2.5f
#define TOPKN 128

typedef __attribute__((ext_vector_type(8))) short bf16x8;
typedef __attribute__((ext_vector_type(4))) float f32x4;
typedef __attribute__((ext_vector_type(4))) unsigned short u16x4;

// ---- ws float offsets ----
#define OFF_QB   0u            // f32 [8][2048][80]
#define OFF_OB   1310720u      // f32 [2048][640]
#define OFF_QH   2621440u      // bf16 [8][2048][96]
#define OFF_QL   3407872u
#define OFF_KCH  4194304u
#define OFF_KSH  4980736u
#define OFF_KSL  5767168u
#define OFF_VCT  6553600u      // bf16 VT_c  [8][80][2048]
#define OFF_VCQT 7208960u      // bf16 VTq_c [8][80][2048]
#define OFF_VST  7864320u      // bf16 VT_s  [8][80][2048]
#define OFF_VSQT 8519680u      // bf16 VTq_s [8][80][2048]
#define OFF_OP   9175040u      // f32 [4][8][2048][80]
#define OFF_SP   14417920u
#define OFF_DEN  19660800u     // f32 [4][8][2048]
#define OFF_MSZ  19726336u
#define OFF_LSZ  19791872u
#define OFF_MCZ  19857408u
#define OFF_LCZ  19922944u
#define OFF_M    19988480u
#define OFF_LAM  20004864u
#define OFF_THR  20006912u
#define OFF_MU   20023296u
#define OFF_RSTD 20023936u
#define OFF_S16  20024576u     // fp16 style   S [8][2048][2048]
#define OFF_SC16 36801792u     // fp16 content S [8][2048][2048]

static __device__ __forceinline__ unsigned short f2bf(float f) {
  unsigned u = __float_as_uint(f);
  return (unsigned short)((u + 0x7FFFu + ((u >> 16) & 1u)) >> 16);
}
static __device__ __forceinline__ float bf2f(unsigned short s) {
  return __uint_as_float(((unsigned)s) << 16);
}
static __device__ __forceinline__ unsigned sk16(unsigned u) {
  return (u & 0x8000u) ? (~u & 0xFFFFu) : (u | 0x8000u);
}

// ---------------- split-bf16 MFMA projection GEMM ---------------------------
// q branch (z=0): 3-term split. K/V branches (z=1,2): 2-term (outputs are
// stored as single bf16, so 2-term error << storage rounding).
__global__ __launch_bounds__(256) void k_projmm(
    const float* __restrict__ x, const float* __restrict__ Wq,
    const float* __restrict__ Wk, const float* __restrict__ Wv,
    const float* __restrict__ Qc, float* __restrict__ qb,
    unsigned short* __restrict__ qh_, unsigned short* __restrict__ ql_,
    unsigned short* __restrict__ kch_,
    unsigned short* __restrict__ vct_, unsigned short* __restrict__ vcqt_)
{
  const float* W = (blockIdx.z == 0) ? Wq : ((blockIdx.z == 1) ? Wk : Wv);
  const int n0 = blockIdx.y * 64, c0 = blockIdx.x * 64;
  const int tid = threadIdx.x;
  const int w = tid >> 6, l = tid & 63;
  const int cc = l & 15, g = l >> 4;
  const bool full3 = (blockIdx.z == 0);

  __shared__ unsigned short sXh[64 * 72];
  __shared__ unsigned short sXl[64 * 72];
  __shared__ unsigned short sWh[64 * 72];
  __shared__ unsigned short sWl[64 * 72];

  f32x4 D[4];
#pragma unroll
  for (int ct = 0; ct < 4; ++ct) D[ct] = (f32x4){0.f, 0.f, 0.f, 0.f};

  for (int k0 = 0; k0 < QD; k0 += 64) {
    __syncthreads();
#pragma unroll
    for (int it = 0; it < 4; ++it) {
      int f = tid + it * 256;
      int row = f >> 4, col4 = f & 15;
      float4 xa = *(const float4*)(x + (size_t)(n0 + row) * QD + k0 + col4 * 4);
      float4 wa = *(const float4*)(W + (size_t)(c0 + row) * QD + k0 + col4 * 4);
      u16x4 xh, xl, wh, wl;
      float xv[4] = {xa.x, xa.y, xa.z, xa.w};
      float wv[4] = {wa.x, wa.y, wa.z, wa.w};
#pragma unroll
      for (int j = 0; j < 4; ++j) {
        unsigned short h1 = f2bf(xv[j]);
        xh[j] = h1; xl[j] = f2bf(xv[j] - bf2f(h1));
        unsigned short h2 = f2bf(wv[j]);
        wh[j] = h2; wl[j] = f2bf(wv[j] - bf2f(h2));
      }
      *(u16x4*)&sXh[row * 72 + col4 * 4] = xh;
      *(u16x4*)&sXl[row * 72 + col4 * 4] = xl;
      *(u16x4*)&sWh[row * 72 + col4 * 4] = wh;
      *(u16x4*)&sWl[row * 72 + col4 * 4] = wl;
    }
    __syncthreads();
    bf16x8 ah[2], al[2];
#pragma unroll
    for (int kc = 0; kc < 2; ++kc) {
      ah[kc] = *(const bf16x8*)&sXh[(w * 16 + cc) * 72 + kc * 32 + g * 8];
      al[kc] = *(const bf16x8*)&sXl[(w * 16 + cc) * 72 + kc * 32 + g * 8];
    }
#pragma unroll
    for (int ct = 0; ct < 4; ++ct) {
#pragma unroll
      for (int kc = 0; kc < 2; ++kc) {
        bf16x8 bh = *(const bf16x8*)&sWh[(ct * 16 + cc) * 72 + kc * 32 + g * 8];
        bf16x8 bl = *(const bf16x8*)&sWl[(ct * 16 + cc) * 72 + kc * 32 + g * 8];
        D[ct] = __builtin_amdgcn_mfma_f32_16x16x32_bf16(ah[kc], bh, D[ct], 0, 0, 0);
        D[ct] = __builtin_amdgcn_mfma_f32_16x16x32_bf16(ah[kc], bl, D[ct], 0, 0, 0);
        if (full3)
          D[ct] = __builtin_amdgcn_mfma_f32_16x16x32_bf16(al[kc], bh, D[ct], 0, 0, 0);
      }
    }
  }
#pragma unroll
  for (int ct = 0; ct < 4; ++ct) {
#pragma unroll
    for (int r = 0; r < 4; ++r) {
      int n = n0 + w * 16 + g * 4 + r;
      int ccol = c0 + ct * 16 + cc;
      int h = ccol / DH, d = ccol - h * DH;
      size_t i80 = ((size_t)h * NTOK + n) * 80 + d;
      size_t i96 = ((size_t)h * NTOK + n) * 96 + d;
      float val = D[ct][r];
      if (blockIdx.z == 0) {
        val = GAMMA_F * Qc[i80] + (1.f - GAMMA_F) * val;
        qb[i80] = val;
        unsigned short hs = f2bf(val);
        qh_[i96] = hs;
        ql_[i96] = f2bf(val - bf2f(hs));
      } else if (blockIdx.z == 1) {
        kch_[i96] = f2bf(val);
      } else {
        size_t iT = (((size_t)h * 80 + d) << 11) + n;   // VT_c[h][d][n]
        vct_[iT]  = f2bf(val);
        vcqt_[iT] = f2bf(val * val);
      }
    }
  }
}

// ---------------- style inputs: K split + pads; V transposed to VT ----------
__global__ __launch_bounds__(256) void k_cvt(
    const float* __restrict__ Ks, const float* __restrict__ Vs,
    unsigned short* __restrict__ Ksh, unsigned short* __restrict__ Ksl,
    unsigned short* __restrict__ VTs, unsigned short* __restrict__ VTqs,
    unsigned short* __restrict__ qh_, unsigned short* __restrict__ ql_,
    unsigned short* __restrict__ kch_)
{
  const int h = blockIdx.y;
  const int n0 = blockIdx.x * 64;
  const int tid = threadIdx.x;
  __shared__ unsigned short sVT[80 * 68];
  __shared__ unsigned short sVQ[80 * 68];

  for (int f = tid; f < 1280; f += 256) {
    int rr = f / 20, dc = f % 20;
    size_t i80 = ((size_t)h * NTOK + n0 + rr) * 80 + dc * 4;
    size_t i96 = ((size_t)h * NTOK + n0 + rr) * 96 + dc * 4;
    float4 kv = *(const float4*)(Ks + i80);
    float kvv[4] = {kv.x, kv.y, kv.z, kv.w};
    u16x4 kh, kl;
#pragma unroll
    for (int j = 0; j < 4; ++j) {
      unsigned short hs = f2bf(kvv[j]);
      kh[j] = hs; kl[j] = f2bf(kvv[j] - bf2f(hs));
    }
    *(u16x4*)(Ksh + i96) = kh;
    *(u16x4*)(Ksl + i96) = kl;
    float4 vv = *(const float4*)(Vs + i80);
    float vvv[4] = {vv.x, vv.y, vv.z, vv.w};
#pragma unroll
    for (int j = 0; j < 4; ++j) {
      int d = dc * 4 + j;
      sVT[d * 68 + rr] = f2bf(vvv[j]);
      sVQ[d * 68 + rr] = f2bf(vvv[j] * vvv[j]);
    }
  }
  for (int f = tid; f < 1024; f += 256) {
    int rr = f >> 4, dcol = 80 + (f & 15);
    size_t i96 = ((size_t)h * NTOK + n0 + rr) * 96 + dcol;
    Ksh[i96] = 0; Ksl[i96] = 0; qh_[i96] = 0; ql_[i96] = 0; kch_[i96] = 0;
  }
  __syncthreads();
  for (int f = tid; f < 640; f += 256) {
    int d = f >> 3, kp8 = f & 7;
    size_t iT = (((size_t)h * 80 + d) << 11) + n0 + kp8 * 8;
    *(bf16x8*)(VTs + iT)  = *(const bf16x8*)&sVT[d * 68 + kp8 * 8];
    *(bf16x8*)(VTqs + iT) = *(const bf16x8*)&sVQ[d * 68 + kp8 * 8];
  }
}

// ---------------- per-(h,d) mean / rstd of q over tokens --------------------
__global__ __launch_bounds__(128) void k_qstats(
    const float* __restrict__ qb, float* __restrict__ mu, float* __restrict__ rstd)
{
  const int h = blockIdx.x / DH, d = blockIdx.x % DH;
  const int tid = threadIdx.x;
  float s = 0.f, s2 = 0.f;
  for (int n = tid; n < NTOK; n += 128) {
    float v = qb[((size_t)h * NTOK + n) * 80 + d];
    s += v; s2 = fmaf(v, v, s2);
  }
#pragma unroll
  for (int off = 32; off; off >>= 1) { s += __shfl_xor(s, off, 64); s2 += __shfl_xor(s2, off, 64); }
  __shared__ float sh[4];
  if ((tid & 63) == 0) { sh[(tid >> 6) * 2] = s; sh[(tid >> 6) * 2 + 1] = s2; }
  __syncthreads();
  if (tid == 0) {
    float S = sh[0] + sh[2], S2 = sh[1] + sh[3];
    float mval = S * (1.f / NTOK);
    float var = S2 * (1.f / NTOK) - mval * mval;
    mu[h * DH + d] = mval;
    rstd[h * DH + d] = rsqrtf(var + 1e-5f);
  }
}

// ---------------- pass A (z=4, XCD-swizzled): logits -> fp16 S / Sc; LSE ----
// Fixed-base LSE (logits bounded, |s| << 88): lse += exp(s), m = fmax(m,s).
// S tiles assembled in WAVE-PRIVATE LDS then stored as coalesced uint4.
__global__ __launch_bounds__(256) void k_passA(
    const unsigned short* __restrict__ qh_, const unsigned short* __restrict__ ql_,
    const unsigned short* __restrict__ Ksh, const unsigned short* __restrict__ Ksl,
    const unsigned short* __restrict__ kch_,
    unsigned short* __restrict__ S16, unsigned short* __restrict__ Sc16,
    float* __restrict__ mSz, float* __restrict__ lSz,
    float* __restrict__ mCz, float* __restrict__ lCz)
{
  const int bid = blockIdx.x;
  const int swz = (bid & 7) * 128 + (bid >> 3);
  const int q0 = (swz & 31) * 64;
  const int h  = (swz >> 5) & 7;
  const int z  = swz >> 8;
  const int tid = threadIdx.x;
  const int w = tid >> 6, l = tid & 63;
  const int c = l & 15, g = l >> 4;

  __shared__ unsigned short sKh[64 * 104];
  __shared__ unsigned short sKl[64 * 104];
  __shared__ unsigned short sS[4 * 16 * 68];   // wave-private 16x64 (stride 68)
  unsigned short* sSw = sS + w * 16 * 68;
  const int orow = l >> 2, oq = l & 3;         // output-store mapping

  bf16x8 qhf[3], qlf[3];
  {
    const size_t qrow = ((size_t)h * NTOK + q0 + w * 16 + c) * 96;
#pragma unroll
    for (int kc = 0; kc < 3; ++kc) {
      qhf[kc] = *(const bf16x8*)(qh_ + qrow + kc * 32 + g * 8);
      qlf[kc] = *(const bf16x8*)(ql_ + qrow + kc * 32 + g * 8);
    }
  }
  float m[4], lse[4], mc[4], lc[4];
#pragma unroll
  for (int r = 0; r < 4; ++r) { m[r] = -INFINITY; lse[r] = 0.f; mc[r] = -INFINITY; lc[r] = 0.f; }

  // ---- style: 8 key tiles of 64 ----
  for (int t = 0; t < 8; ++t) {
    const size_t kbase = ((size_t)h * NTOK + z * 512 + t * 64) * 96;
    __syncthreads();
    for (int f = tid; f < 768; f += 256) {
      int row = f / 12, ch = f % 12;
      *(bf16x8*)(sKh + row * 104 + ch * 8) = *(const bf16x8*)(Ksh + kbase + row * 96 + ch * 8);
      *(bf16x8*)(sKl + row * 104 + ch * 8) = *(const bf16x8*)(Ksl + kbase + row * 96 + ch * 8);
    }
    __syncthreads();
#pragma unroll
    for (int ct = 0; ct < 4; ++ct) {
      f32x4 D = {0.f, 0.f, 0.f, 0.f};
      const int krow = (ct * 16 + c) * 104 + g * 8;
#pragma unroll
      for (int kc = 0; kc < 3; ++kc) {
        bf16x8 bh = *(const bf16x8*)(sKh + krow + kc * 32);
        D = __builtin_amdgcn_mfma_f32_16x16x32_bf16(qhf[kc], bh, D, 0, 0, 0);
      }
#pragma unroll
      for (int kc = 0; kc < 3; ++kc) {
        bf16x8 bl = *(const bf16x8*)(sKl + krow + kc * 32);
        D = __builtin_amdgcn_mfma_f32_16x16x32_bf16(qhf[kc], bl, D, 0, 0, 0);
      }
#pragma unroll
      for (int kc = 0; kc < 3; ++kc) {
        bf16x8 bh = *(const bf16x8*)(sKh + krow + kc * 32);
        D = __builtin_amdgcn_mfma_f32_16x16x32_bf16(qlf[kc], bh, D, 0, 0, 0);
      }
#pragma unroll
      for (int r = 0; r < 4; ++r) {
        float s = D[r] * TSCALE_F;
        sSw[(g * 4 + r) * 68 + ct * 16 + c] = __half_as_ushort(__float2half(s));
        lse[r] += __expf(s);
        m[r] = fmaxf(m[r], s);
      }
    }
    // wave-private: coalesced store of the 16x64 tile (no barrier needed)
    {
      size_t gbase = ((size_t)h * NTOK + q0 + w * 16 + orow) * 2048 + z * 512 + t * 64 + oq * 16;
      *(uint4*)(S16 + gbase)     = *(const uint4*)&sSw[orow * 68 + oq * 16];
      *(uint4*)(S16 + gbase + 8) = *(const uint4*)&sSw[orow * 68 + oq * 16 + 8];
    }
  }
  // ---- content: 8 key tiles ----
  for (int t = 0; t < 8; ++t) {
    const size_t kbase = ((size_t)h * NTOK + z * 512 + t * 64) * 96;
    __syncthreads();
    for (int f = tid; f < 768; f += 256) {
      int row = f / 12, ch = f % 12;
      *(bf16x8*)(sKh + row * 104 + ch * 8) = *(const bf16x8*)(kch_ + kbase + row * 96 + ch * 8);
    }
    __syncthreads();
#pragma unroll
    for (int ct = 0; ct < 4; ++ct) {
      f32x4 D = {0.f, 0.f, 0.f, 0.f};
      const int krow = (ct * 16 + c) * 104 + g * 8;
#pragma unroll
      for (int kc = 0; kc < 3; ++kc) {
        bf16x8 bh = *(const bf16x8*)(sKh + krow + kc * 32);
        D = __builtin_amdgcn_mfma_f32_16x16x32_bf16(qhf[kc], bh, D, 0, 0, 0);
      }
#pragma unroll
      for (int r = 0; r < 4; ++r) {
        float s = D[r] * SCALE_F;
        sSw[(g * 4 + r) * 68 + ct * 16 + c] = __half_as_ushort(__float2half(s));
        lc[r] += __expf(s);
        mc[r] = fmaxf(mc[r], s);
      }
    }
    {
      size_t gbase = ((size_t)h * NTOK + q0 + w * 16 + orow) * 2048 + z * 512 + t * 64 + oq * 16;
      *(uint4*)(Sc16 + gbase)     = *(const uint4*)&sSw[orow * 68 + oq * 16];
      *(uint4*)(Sc16 + gbase + 8) = *(const uint4*)&sSw[orow * 68 + oq * 16 + 8];
    }
  }
  // merge across the 16 col-lanes (plain sum/max; fixed base)
#pragma unroll
  for (int off = 1; off < 16; off <<= 1) {
#pragma unroll
    for (int r = 0; r < 4; ++r) {
      lse[r] += __shfl_xor(lse[r], off, 64);
      m[r] = fmaxf(m[r], __shfl_xor(m[r], off, 64));
      lc[r] += __shfl_xor(lc[r], off, 64);
      mc[r] = fmaxf(mc[r], __shfl_xor(mc[r], off, 64));
    }
  }
  if (c == 0) {
    size_t base = (size_t)(z * 8 + h) * NTOK + q0 + w * 16 + g * 4;
#pragma unroll
    for (int r = 0; r < 4; ++r) {
      mSz[base + r] = m[r]; lSz[base + r] = lse[r];
      mCz[base + r] = mc[r]; lCz[base + r] = lc[r];
    }
  }
}

// ---------------- gate: combine 4 z-slices (fixed-base sums), lambda, M -----
__global__ __launch_bounds__(256) void k_gate(
    const float* __restrict__ mSz, const float* __restrict__ lSz,
    const float* __restrict__ mCz, const float* __restrict__ lCz,
    float* __restrict__ M_, float* __restrict__ lam_)
{
  int n = blockIdx.x * 256 + threadIdx.x;
  if (n >= NTOK) return;
  float msf[NH], mcf[NH], sum = 0.f;
#pragma unroll
  for (int h = 0; h < NH; ++h) {
    float mm = -INFINITY, cm = -INFINITY, ls = 0.f, lcs = 0.f;
#pragma unroll
    for (int zz = 0; zz < 4; ++zz) {
      mm = fmaxf(mm, mSz[(size_t)(zz * 8 + h) * NTOK + n]);
      cm = fmaxf(cm, mCz[(size_t)(zz * 8 + h) * NTOK + n]);
      ls  += lSz[(size_t)(zz * 8 + h) * NTOK + n];
      lcs += lCz[(size_t)(zz * 8 + h) * NTOK + n];
    }
    float lse_s = __logf(ls);
    float lse_c = __logf(lcs);
    msf[h] = mm; mcf[h] = cm;
    sum += fminf(fmaxf(lse_s - lse_c, -20.f), 20.f);
  }
  float lam = 1.f + (LMAX_F - 1.f) * (1.f / (1.f + __expf(-sum * (1.f / NH))));
  lam_[n] = lam;
#pragma unroll
  for (int h = 0; h < NH; ++h)
    M_[h * NTOK + n] = fmaxf(lam * msf[h], mcf[h]);
}

// ---------------- top-k threshold: 16-bit ballot bisection on fp16 S --------
__global__ __launch_bounds__(512) void k_topk(const unsigned short* __restrict__ S16,
                                              unsigned* __restrict__ thr_)
{
  const int h = blockIdx.y;
  const int n = blockIdx.x * 8 + (threadIdx.x >> 6);
  const int l = threadIdx.x & 63;
  const unsigned short* Srow = S16 + ((size_t)h * NTOK + n) * 2048;
  unsigned kv[32];
#pragma unroll
  for (int t = 0; t < 4; ++t) {
    uint4 v = ((const uint4*)Srow)[t * 64 + l];
    unsigned dw[4] = {v.x, v.y, v.z, v.w};
#pragma unroll
    for (int i = 0; i < 8; ++i) {
      unsigned u = (dw[i >> 1] >> ((i & 1) * 16)) & 0xFFFFu;
      kv[t * 8 + i] = sk16(u);
    }
  }
  unsigned klo = 0u, khi = 65536u;
  for (int it = 0; it < 16; ++it) {
    unsigned mid = (klo + khi) >> 1;
    int cnt = 0;
#pragma unroll
    for (int t = 0; t < 32; ++t)
      cnt += __popcll(__ballot(kv[t] >= mid));
    if (cnt == TOPKN) { klo = mid; break; }
    if (cnt > TOPKN) klo = mid; else khi = mid;
    if (khi - klo <= 1u) break;
  }
  if (l == 0) thr_[h * NTOK + n] = klo;
}

// ---------------- pass B (z=4): pure PV. 16 tiles (8 style + 8 content). ----
__global__ __launch_bounds__(256) void k_passB(
    const unsigned short* __restrict__ VTs, const unsigned short* __restrict__ VTqs,
    const unsigned short* __restrict__ VTc, const unsigned short* __restrict__ VTqc,
    const unsigned short* __restrict__ S16, const unsigned short* __restrict__ Sc16,
    const float* __restrict__ M_, const float* __restrict__ lam_,
    const unsigned* __restrict__ thr_,
    float* __restrict__ oP, float* __restrict__ sP, float* __restrict__ denP)
{
  const int bid = blockIdx.x;
  const int swz = (bid & 7) * 128 + (bid >> 3);
  const int q0 = (swz & 31) * 64;
  const int h  = (swz >> 5) & 7;
  const int z  = swz >> 8;
  const int tid = threadIdx.x;
  const int w = tid >> 6, l = tid & 63;
  const int c = l & 15, g = l >> 4;

  __shared__ unsigned short vT[80 * 72];
  __shared__ unsigned short vqT[80 * 72];

  const int myrow = w * 16 + c;
  const float myM = M_[h * NTOK + q0 + myrow];
  const float myLam = lam_[q0 + myrow];
  const unsigned myThr = thr_[h * NTOK + q0 + myrow];

  const size_t srow = ((size_t)h * NTOK + q0 + myrow) * 2048 + g * 8;
  const int d0 = tid >> 3, kp8 = tid & 7;
  const size_t vr0 = (((size_t)h * 80 + d0) << 11) + kp8 * 8;
  const size_t vr1 = (((size_t)h * 80 + d0 + 32) << 11) + kp8 * 8;
  const size_t vr2 = (((size_t)h * 80 + d0 + 64) << 11) + kp8 * 8;
  const bool third = (tid < 128);

  f32x4 oacc[5], sacc[5];
#pragma unroll
  for (int dt = 0; dt < 5; ++dt) { oacc[dt] = (f32x4){0.f,0.f,0.f,0.f}; sacc[dt] = (f32x4){0.f,0.f,0.f,0.f}; }
  float den = 0.f;

  for (int t = 0; t < 16; ++t) {
    const bool style = (t < 8);
    const int k0 = z * 512 + (t & 7) * 64;
    const unsigned short* Sp = style ? S16 : Sc16;
    const unsigned short* Vp = style ? VTs : VTc;
    const unsigned short* Vq = style ? VTqs : VTqc;
    uint4 s0 = *(const uint4*)(Sp + srow + k0);
    uint4 s1 = *(const uint4*)(Sp + srow + k0 + 32);
    bf16x8 v0 = *(const bf16x8*)(Vp + vr0 + k0);
    bf16x8 v1 = *(const bf16x8*)(Vp + vr1 + k0);
    bf16x8 u0 = *(const bf16x8*)(Vq + vr0 + k0);
    bf16x8 u1 = *(const bf16x8*)(Vq + vr1 + k0);
    bf16x8 v2, u2;
    if (third) {
      v2 = *(const bf16x8*)(Vp + vr2 + k0);
      u2 = *(const bf16x8*)(Vq + vr2 + k0);
    }
    __syncthreads();
    *(bf16x8*)&vT[d0 * 72 + kp8 * 8] = v0;
    *(bf16x8*)&vqT[d0 * 72 + kp8 * 8] = u0;
    *(bf16x8*)&vT[(d0 + 32) * 72 + kp8 * 8] = v1;
    *(bf16x8*)&vqT[(d0 + 32) * 72 + kp8 * 8] = u1;
    if (third) {
      *(bf16x8*)&vT[(d0 + 64) * 72 + kp8 * 8] = v2;
      *(bf16x8*)&vqT[(d0 + 64) * 72 + kp8 * 8] = u2;
    }
    __syncthreads();
    bf16x8 pa0, pa1;
    {
      unsigned dw0[4] = {s0.x, s0.y, s0.z, s0.w};
      unsigned dw1[4] = {s1.x, s1.y, s1.z, s1.w};
#pragma unroll
      for (int i = 0; i < 8; ++i) {
        unsigned ua = (dw0[i >> 1] >> ((i & 1) * 16)) & 0xFFFFu;
        float sa = __half2float(__ushort_as_half((unsigned short)ua));
        float wa = style ? ((sk16(ua) >= myThr) ? __expf(myLam * sa - myM) : 0.f)
                         : __expf(sa - myM);
        den += wa;
        pa0[i] = (short)f2bf(wa);
        unsigned ub = (dw1[i >> 1] >> ((i & 1) * 16)) & 0xFFFFu;
        float sb = __half2float(__ushort_as_half((unsigned short)ub));
        float wb = style ? ((sk16(ub) >= myThr) ? __expf(myLam * sb - myM) : 0.f)
                         : __expf(sb - myM);
        den += wb;
        pa1[i] = (short)f2bf(wb);
      }
    }
#pragma unroll
    for (int dt = 0; dt < 5; ++dt) {
      bf16x8 bv0  = *(const bf16x8*)&vT[(dt * 16 + c) * 72 + g * 8];
      bf16x8 bvq0 = *(const bf16x8*)&vqT[(dt * 16 + c) * 72 + g * 8];
      bf16x8 bv1  = *(const bf16x8*)&vT[(dt * 16 + c) * 72 + 32 + g * 8];
      bf16x8 bvq1 = *(const bf16x8*)&vqT[(dt * 16 + c) * 72 + 32 + g * 8];
      oacc[dt] = __builtin_amdgcn_mfma_f32_16x16x32_bf16(pa0, bv0, oacc[dt], 0, 0, 0);
      sacc[dt] = __builtin_amdgcn_mfma_f32_16x16x32_bf16(pa0, bvq0, sacc[dt], 0, 0, 0);
      oacc[dt] = __builtin_amdgcn_mfma_f32_16x16x32_bf16(pa1, bv1, oacc[dt], 0, 0, 0);
      sacc[dt] = __builtin_amdgcn_mfma_f32_16x16x32_bf16(pa1, bvq1, sacc[dt], 0, 0, 0);
    }
  }
  den += __shfl_xor(den, 16, 64);
  den += __shfl_xor(den, 32, 64);
  if (g == 0) denP[(size_t)(z * 8 + h) * NTOK + q0 + myrow] = den;
  const size_t base = (size_t)(z * 8 + h) * NTOK + q0 + w * 16;
#pragma unroll
  for (int dt = 0; dt < 5; ++dt)
#pragma unroll
    for (int r = 0; r < 4; ++r) {
      size_t o = (base + g * 4 + r) * 80 + dt * 16 + c;
      oP[o] = oacc[dt][r];
      sP[o] = sacc[dt][r];
    }
}

// ---------------- finalize: combine 4 z-slices + AdaIN epilogue -------------
__global__ __launch_bounds__(256) void k_fin(
    const float* __restrict__ oP, const float* __restrict__ sP,
    const float* __restrict__ denP, const float* __restrict__ qb,
    const float* __restrict__ mu, const float* __restrict__ rstd,
    const float* __restrict__ gate, float* __restrict__ Ob)
{
  int idx = blockIdx.x * 256 + threadIdx.x;
  int h = idx / (NTOK * 80);
  int rem = idx - h * (NTOK * 80);
  int n = rem / 80, d = rem - n * 80;
  float den = 0.f, o = 0.f, sq = 0.f;
#pragma unroll
  for (int zz = 0; zz < 4; ++zz) {
    den += denP[(size_t)(zz * 8 + h) * NTOK + n];
    size_t p = ((size_t)(zz * 8 + h) * NTOK + n) * 80 + d;
    o += oP[p];
    sq += sP[p];
  }
  o /= den;
  sq /= den;
  float vstd = sqrtf(fmaxf(sq - o * o, 1e-5f));
  float g = tanhf(gate[0]);
  float qn = (qb[((size_t)h * NTOK + n) * 80 + d] - mu[h * DH + d]) * rstd[h * DH + d];
  Ob[(size_t)n * QD + h * DH + d] = fmaf(g * vstd, qn, o);
}

// ---------------- final projection: split-bf16 MFMA, out = Ob@Wo^T + bo -----
__global__ __launch_bounds__(256) void k_finalmm(
    const float* __restrict__ A, const float* __restrict__ W,
    const float* __restrict__ bias, float* __restrict__ out)
{
  const int n0 = blockIdx.y * 64, c0 = blockIdx.x * 64;
  const int tid = threadIdx.x;
  const int w = tid >> 6, l = tid & 63;
  const int cc = l & 15, g = l >> 4;

  __shared__ unsigned short sXh[64 * 72];
  __shared__ unsigned short sXl[64 * 72];
  __shared__ unsigned short sWh[64 * 72];
  __shared__ unsigned short sWl[64 * 72];

  f32x4 D[4];
#pragma unroll
  for (int ct = 0; ct < 4; ++ct) D[ct] = (f32x4){0.f, 0.f, 0.f, 0.f};

  for (int k0 = 0; k0 < QD; k0 += 64) {
    __syncthreads();
#pragma unroll
    for (int it = 0; it < 4; ++it) {
      int f = tid + it * 256;
      int row = f >> 4, col4 = f & 15;
      float4 xa = *(const float4*)(A + (size_t)(n0 + row) * QD + k0 + col4 * 4);
      float4 wa = *(const float4*)(W + (size_t)(c0 + row) * QD + k0 + col4 * 4);
      u16x4 xh, xl, wh, wl;
      float xv[4] = {xa.x, xa.y, xa.z, xa.w};
      float wv[4] = {wa.x, wa.y, wa.z, wa.w};
#pragma unroll
      for (int j = 0; j < 4; ++j) {
        unsigned short h1 = f2bf(xv[j]);
        xh[j] = h1; xl[j] = f2bf(xv[j] - bf2f(h1));
        unsigned short h2 = f2bf(wv[j]);
        wh[j] = h2; wl[j] = f2bf(wv[j] - bf2f(h2));
      }
      *(u16x4*)&sXh[row * 72 + col4 * 4] = xh;
      *(u16x4*)&sXl[row * 72 + col4 * 4] = xl;
      *(u16x4*)&sWh[row * 72 + col4 * 4] = wh;
      *(u16x4*)&sWl[row * 72 + col4 * 4] = wl;
    }
    __syncthreads();
    bf16x8 ah[2], al[2];
#pragma unroll
    for (int kc = 0; kc < 2; ++kc) {
      ah[kc] = *(const bf16x8*)&sXh[(w * 16 + cc) * 72 + kc * 32 + g * 8];
      al[kc] = *(const bf16x8*)&sXl[(w * 16 + cc) * 72 + kc * 32 + g * 8];
    }
#pragma unroll
    for (int ct = 0; ct < 4; ++ct) {
#pragma unroll
      for (int kc = 0; kc < 2; ++kc) {
        bf16x8 bh = *(const bf16x8*)&sWh[(ct * 16 + cc) * 72 + kc * 32 + g * 8];
        bf16x8 bl = *(const bf16x8*)&sWl[(ct * 16 + cc) * 72 + kc * 32 + g * 8];
        D[ct] = __builtin_amdgcn_mfma_f32_16x16x32_bf16(ah[kc], bh, D[ct], 0, 0, 0);
        D[ct] = __builtin_amdgcn_mfma_f32_16x16x32_bf16(ah[kc], bl, D[ct], 0, 0, 0);
        D[ct] = __builtin_amdgcn_mfma_f32_16x16x32_bf16(al[kc], bh, D[ct], 0, 0, 0);
      }
    }
  }
#pragma unroll
  for (int ct = 0; ct < 4; ++ct) {
#pragma unroll
    for (int r = 0; r < 4; ++r) {
      int n = n0 + w * 16 + g * 4 + r;
      int ccol = c0 + ct * 16 + cc;
      out[(size_t)n * QD + ccol] = D[ct][r] + bias[ccol];
    }
  }
}

extern "C" void kernel_launch(void* const* d_in, const int* in_sizes, int n_in,
                              void* d_out, int out_size, void* d_ws, size_t ws_size,
                              hipStream_t stream) {
  const float* x    = (const float*)d_in[0];
  const float* Qc   = (const float*)d_in[1];
  const float* Ks   = (const float*)d_in[2];
  const float* Vs   = (const float*)d_in[3];
  const float* Wq   = (const float*)d_in[4];
  const float* Wk   = (const float*)d_in[5];
  const float* Wv   = (const float*)d_in[6];
  const float* Wo   = (const float*)d_in[7];
  const float* bo   = (const float*)d_in[8];
  const float* gate = (const float*)d_in[9];
  float* out = (float*)d_out;
  float* w = (float*)d_ws;

  float* qb   = w + OFF_QB;
  float* Ob   = w + OFF_OB;
  unsigned short* qh_  = (unsigned short*)(w + OFF_QH);
  unsigned short* ql_  = (unsigned short*)(w + OFF_QL);
  unsigned short* kch_ = (unsigned short*)(w + OFF_KCH);
  unsigned short* Ksh  = (unsigned short*)(w + OFF_KSH);
  unsigned short* Ksl  = (unsigned short*)(w + OFF_KSL);
  unsigned short* VTc  = (unsigned short*)(w + OFF_VCT);
  unsigned short* VTqc = (unsigned short*)(w + OFF_VCQT);
  unsigned short* VTs  = (unsigned short*)(w + OFF_VST);
  unsigned short* VTqs = (unsigned short*)(w + OFF_VSQT);
  float* oP   = w + OFF_OP;
  float* sP   = w + OFF_SP;
  float* denP = w + OFF_DEN;
  float* mSz  = w + OFF_MSZ;
  float* lSz  = w + OFF_LSZ;
  float* mCz  = w + OFF_MCZ;
  float* lCz  = w + OFF_LCZ;
  float* M_   = w + OFF_M;
  float* lam_ = w + OFF_LAM;
  unsigned* thr_ = (unsigned*)(w + OFF_THR);
  float* mu   = w + OFF_MU;
  float* rstd = w + OFF_RSTD;
  unsigned short* S16  = (unsigned short*)(w + OFF_S16);
  unsigned short* Sc16 = (unsigned short*)(w + OFF_SC16);

  k_projmm<<<dim3(10, 32, 3), 256, 0, stream>>>(x, Wq, Wk, Wv, Qc, qb, qh_, ql_, kch_, VTc, VTqc);
  k_cvt<<<dim3(32, 8), 256, 0, stream>>>(Ks, Vs, Ksh, Ksl, VTs, VTqs, qh_, ql_, kch_);
  k_qstats<<<dim3(640), 128, 0, stream>>>(qb, mu, rstd);
  k_passA<<<dim3(1024), 256, 0, stream>>>(qh_, ql_, Ksh, Ksl, kch_, S16, Sc16, mSz, lSz, mCz, lCz);
  k_gate<<<dim3(8), 256, 0, stream>>>(mSz, lSz, mCz, lCz, M_, lam_);
  k_topk<<<dim3(256, 8), 512, 0, stream>>>(S16, thr_);
  k_passB<<<dim3(1024), 256, 0, stream>>>(VTs, VTqs, VTc, VTqc, S16, Sc16, M_, lam_, thr_, oP, sP, denP);
  k_fin<<<dim3(5120), 256, 0, stream>>>(oP, sP, denP, qb, mu, rstd, gate, Ob);
  k_finalmm<<<dim3(10, 32), 256, 0, stream>>>(Ob, Wo, bo, out);
}